// Round 1
// baseline (959.932 us; speedup 1.0000x reference)
//
#include <hip/hip_runtime.h>
#include <stdint.h>
#include <stddef.h>

// ---- problem constants ----
#define BATCH  16
#define HEADS  8
#define NTOK   4096      // H*W
#define DHEAD  64
#define CDIM   512
#define FDIM   1536      // 3*C
#define MROWS  65536     // BATCH*NTOK

typedef short bf16x8 __attribute__((ext_vector_type(8)));
typedef short bf16x4 __attribute__((ext_vector_type(4)));
typedef float fx4    __attribute__((ext_vector_type(4)));

__device__ __forceinline__ uint16_t f2bf(float f) {
    uint32_t u = __float_as_uint(f);
    return (uint16_t)((u + 0x7FFFu + ((u >> 16) & 1u)) >> 16); // RNE
}
__device__ __forceinline__ float bf2f(uint16_t u) {
    return __uint_as_float(((uint32_t)u) << 16);
}

// ---------------------------------------------------------------------------
// prep: Wt[f][c] = bf16(qkv_w[c][f]); Pt[f][c] = bf16(proj_w[c][f]); zero Sq/Sk/G
// ---------------------------------------------------------------------------
__global__ void prep_kernel(const float* __restrict__ qkv_w,
                            const float* __restrict__ proj_w,
                            uint16_t* __restrict__ Wt, uint16_t* __restrict__ Pt,
                            float* __restrict__ zbase) {
    const int NW = FDIM * CDIM;            // 786432
    const int NP = CDIM * CDIM;            // 262144
    const int NZ = 128 * DHEAD * 2 + 128 * DHEAD * DHEAD; // Sq+Sk+G floats
    const int total = NW + NP + NZ;
    for (int i = blockIdx.x * blockDim.x + threadIdx.x; i < total;
         i += gridDim.x * blockDim.x) {
        if (i < NW) {
            int f = i >> 9, c = i & 511;
            Wt[i] = f2bf(qkv_w[(size_t)c * FDIM + f]);
        } else if (i < NW + NP) {
            int j = i - NW;
            int f = j >> 9, c = j & 511;
            Pt[j] = f2bf(proj_w[(size_t)c * CDIM + f]);
        } else {
            zbase[i - NW - NP] = 0.0f;
        }
    }
}

// ---------------------------------------------------------------------------
// qkv GEMM: qkv[M][1536] = bf16(X[M][512]) @ Wt[1536][512]^T + bias(flat col)
// 128x128 tile, BK=64, 4 waves (2x2), each wave 64x64 via 4x4 mfma 16x16x32.
// ---------------------------------------------------------------------------
__global__ __launch_bounds__(256) void gemm_qkv_kernel(
        const float* __restrict__ X, const uint16_t* __restrict__ Wt,
        const float* __restrict__ q_bias, const float* __restrict__ v_bias,
        uint16_t* __restrict__ qkv) {
    __shared__ uint16_t As[128][72];  // pad 64->72: 144B row stride, 2-way max
    __shared__ uint16_t Bs[128][72];
    const int bx = blockIdx.x;
    const int tn = bx % 12, tm = bx / 12;   // consecutive blocks share A tile
    const int gm = tm * 128, gn = tn * 128;
    const int t = threadIdx.x;
    const int lane = t & 63, w = t >> 6;
    const int wm = w >> 1, wn = w & 1;
    const int l15 = lane & 15, lg = lane >> 4;
    fx4 acc[4][4] = {};
    const int srow = t >> 1, sseg = (t & 1) * 32;
    for (int k0 = 0; k0 < 512; k0 += 64) {
        __syncthreads();
        {   // stage A (fp32 -> bf16)
            const float* src = X + (size_t)(gm + srow) * 512 + (k0 + sseg);
            uint16_t* dst = &As[srow][sseg];
            #pragma unroll
            for (int j = 0; j < 4; j++) {
                fx4 v0 = reinterpret_cast<const fx4*>(src)[2 * j];
                fx4 v1 = reinterpret_cast<const fx4*>(src)[2 * j + 1];
                union { bf16x8 v; uint16_t u[8]; } pk;
                #pragma unroll
                for (int e = 0; e < 4; e++) { pk.u[e] = f2bf(v0[e]); pk.u[4 + e] = f2bf(v1[e]); }
                reinterpret_cast<bf16x8*>(dst)[j] = pk.v;
            }
            // stage B (already bf16)
            const uint16_t* srcB = Wt + (size_t)(gn + srow) * 512 + (k0 + sseg);
            uint16_t* dstB = &Bs[srow][sseg];
            #pragma unroll
            for (int j = 0; j < 4; j++)
                reinterpret_cast<bf16x8*>(dstB)[j] = reinterpret_cast<const bf16x8*>(srcB)[j];
        }
        __syncthreads();
        #pragma unroll
        for (int ks = 0; ks < 2; ks++) {
            const int kof = ks * 32 + lg * 8;
            bf16x8 af[4], bfr[4];
            #pragma unroll
            for (int m = 0; m < 4; m++)
                af[m] = *reinterpret_cast<const bf16x8*>(&As[wm * 64 + m * 16 + l15][kof]);
            #pragma unroll
            for (int n = 0; n < 4; n++)
                bfr[n] = *reinterpret_cast<const bf16x8*>(&Bs[wn * 64 + n * 16 + l15][kof]);
            #pragma unroll
            for (int m = 0; m < 4; m++)
                #pragma unroll
                for (int n = 0; n < 4; n++)
                    acc[m][n] = __builtin_amdgcn_mfma_f32_16x16x32_bf16(
                        af[m], bfr[n], acc[m][n], 0, 0, 0);
        }
    }
    #pragma unroll
    for (int m = 0; m < 4; m++) {
        #pragma unroll
        for (int n = 0; n < 4; n++) {
            const int col = gn + wn * 64 + n * 16 + l15;
            const float bias = (col < 512) ? q_bias[col]
                              : ((col < 1024) ? 0.0f : v_bias[col - 1024]);
            #pragma unroll
            for (int r = 0; r < 4; r++) {
                const int row = gm + wm * 64 + m * 16 + lg * 4 + r;
                qkv[(size_t)row * FDIM + col] = f2bf(acc[m][n][r] + bias);
            }
        }
    }
}

// ---------------------------------------------------------------------------
// sumsq: Sq[bh][d] = sum_n q^2 ; Sk likewise (atomic partials over 4 n-parts)
// ---------------------------------------------------------------------------
__global__ void sumsq_kernel(const uint16_t* __restrict__ qkv,
                             float* __restrict__ Sq, float* __restrict__ Sk) {
    const int blk = blockIdx.x;            // 512 = 128 bh * 4 parts
    const int bh = blk >> 2, part = blk & 3;
    const int b = bh >> 3, h = bh & 7;
    const int t = threadIdx.x;
    const int d = t & 63, g = t >> 6;
    const uint16_t* base = qkv + (size_t)b * NTOK * FDIM + h * 192;
    float sq = 0.f, sk = 0.f;
    const int nEnd = part * 1024 + 1024;
    for (int n = part * 1024 + g; n < nEnd; n += 4) {
        const uint16_t* row = base + (size_t)n * FDIM;
        float qv = bf2f(row[d]);
        float kv = bf2f(row[64 + d]);
        sq += qv * qv; sk += kv * kv;
    }
    __shared__ float sA[4][64], sB[4][64];
    sA[g][d] = sq; sB[g][d] = sk;
    __syncthreads();
    if (g == 0) {
        atomicAdd(&Sq[bh * 64 + d], sA[0][d] + sA[1][d] + sA[2][d] + sA[3][d]);
        atomicAdd(&Sk[bh * 64 + d], sB[0][d] + sB[1][d] + sB[2][d] + sB[3][d]);
    }
}

// ---------------------------------------------------------------------------
// attn_partial: G[bh][d][e] += sum_{n in chunk} q[n,d]*k[n,e]  (raw, unnormalized)
// grid = 128 bh * 8 chunks; per block: 8 tiles of 64 tokens staged in LDS.
// thread owns 4x4 (d,e) block.
// ---------------------------------------------------------------------------
__global__ __launch_bounds__(256) void attn_partial_kernel(
        const uint16_t* __restrict__ qkv, float* __restrict__ G) {
    const int blk = blockIdx.x;
    const int bh = blk >> 3, chunk = blk & 7;
    const int b = bh >> 3, h = bh & 7;
    const int n0 = chunk * 512;
    const int t = threadIdx.x;
    const int d0 = (t & 15) * 4, e0 = (t >> 4) * 4;
    __shared__ uint16_t qs[64][64];
    __shared__ uint16_t ks_[64][64];
    float g4[4][4] = {};
    const uint16_t* base = qkv + (size_t)b * NTOK * FDIM + h * 192;
    for (int tile = 0; tile < 8; tile++) {
        const int nt = n0 + tile * 64;
        __syncthreads();
        {
            const int tok = t >> 2, seg = (t & 3) * 16;
            const uint16_t* row = base + (size_t)(nt + tok) * FDIM;
            *reinterpret_cast<bf16x8*>(&qs[tok][seg])     = *reinterpret_cast<const bf16x8*>(row + seg);
            *reinterpret_cast<bf16x8*>(&qs[tok][seg + 8]) = *reinterpret_cast<const bf16x8*>(row + seg + 8);
            *reinterpret_cast<bf16x8*>(&ks_[tok][seg])     = *reinterpret_cast<const bf16x8*>(row + 64 + seg);
            *reinterpret_cast<bf16x8*>(&ks_[tok][seg + 8]) = *reinterpret_cast<const bf16x8*>(row + 64 + seg + 8);
        }
        __syncthreads();
        for (int tok = 0; tok < 64; tok++) {
            bf16x4 qr = *reinterpret_cast<const bf16x4*>(&qs[tok][d0]);
            bf16x4 kr = *reinterpret_cast<const bf16x4*>(&ks_[tok][e0]);
            float qf[4], kf[4];
            #pragma unroll
            for (int i = 0; i < 4; i++) {
                qf[i] = bf2f((uint16_t)qr[i]);
                kf[i] = bf2f((uint16_t)kr[i]);
            }
            #pragma unroll
            for (int i = 0; i < 4; i++)
                #pragma unroll
                for (int j = 0; j < 4; j++)
                    g4[i][j] += qf[i] * kf[j];
        }
    }
    float* Gb = G + (size_t)bh * 4096;
    #pragma unroll
    for (int i = 0; i < 4; i++)
        #pragma unroll
        for (int j = 0; j < 4; j++)
            atomicAdd(&Gb[(d0 + i) * 64 + (e0 + j)], g4[i][j]);
}

// ---------------------------------------------------------------------------
// attn_finalize: attn[d][e] = softmax_e( exp(scale_h) * G[d][e] * rq[d] * rk[e] )
// one wave per bh; lane = e.
// ---------------------------------------------------------------------------
__global__ void attn_finalize_kernel(const float* __restrict__ G,
                                     const float* __restrict__ Sq,
                                     const float* __restrict__ Sk,
                                     const float* __restrict__ scale,
                                     float* __restrict__ attn) {
    const int bh = blockIdx.x;
    const int h = bh & 7;
    const int e = threadIdx.x;  // 64
    const float es = expf(scale[h]);
    const float rk = rsqrtf(fmaxf(Sk[bh * 64 + e], 1.55e-5f));
    const float* Gb = G + (size_t)bh * 4096;
    float* Ab = attn + (size_t)bh * 4096;
    for (int d = 0; d < 64; d++) {
        const float rq = rsqrtf(fmaxf(Sq[bh * 64 + d], 1.55e-5f));
        float x = es * Gb[d * 64 + e] * rq * rk;
        float m = x;
        #pragma unroll
        for (int off = 32; off; off >>= 1) m = fmaxf(m, __shfl_xor(m, off, 64));
        float p = expf(x - m);
        float s = p;
        #pragma unroll
        for (int off = 32; off; off >>= 1) s += __shfl_xor(s, off, 64);
        Ab[d * 64 + e] = p / s;
    }
}

// ---------------------------------------------------------------------------
// pv: out_t[b][n][h*64+d] = sum_e attn[bh][d][e] * v[b][n][h][e]   (bf16 out)
// grid = 128 bh * 8 chunks; each thread owns 2 tokens, attn in LDS (broadcast).
// ---------------------------------------------------------------------------
__global__ __launch_bounds__(256) void pv_kernel(
        const uint16_t* __restrict__ qkv, const float* __restrict__ attn,
        uint16_t* __restrict__ out_t) {
    const int blk = blockIdx.x;
    const int bh = blk >> 3, chunk = blk & 7;
    const int b = bh >> 3, h = bh & 7;
    const int t = threadIdx.x;
    __shared__ float As[4096];
    const float* Ab = attn + (size_t)bh * 4096;
    for (int i = t; i < 1024; i += 256)
        reinterpret_cast<fx4*>(As)[i] = reinterpret_cast<const fx4*>(Ab)[i];
    __syncthreads();
    for (int rep = 0; rep < 2; rep++) {
        const int n = chunk * 512 + rep * 256 + t;
        const uint16_t* vrow = qkv + (size_t)(b * NTOK + n) * FDIM + h * 192 + 128;
        float vf[64];
        #pragma unroll
        for (int j = 0; j < 8; j++) {
            bf16x8 vv = reinterpret_cast<const bf16x8*>(vrow)[j];
            #pragma unroll
            for (int e = 0; e < 8; e++) vf[j * 8 + e] = bf2f((uint16_t)vv[e]);
        }
        uint16_t* orow = out_t + (size_t)(b * NTOK + n) * CDIM + h * 64;
        #pragma unroll 2
        for (int dq = 0; dq < 8; dq++) {
            union { bf16x8 v; uint16_t u[8]; } pk;
            for (int dd = 0; dd < 8; dd++) {
                const int d = dq * 8 + dd;
                const fx4* Ar = reinterpret_cast<const fx4*>(&As[d * 64]);
                float a0 = 0.f, a1 = 0.f, a2 = 0.f, a3 = 0.f;
                #pragma unroll
                for (int j = 0; j < 16; j++) {
                    fx4 av = Ar[j];
                    a0 += av[0] * vf[j * 4 + 0];
                    a1 += av[1] * vf[j * 4 + 1];
                    a2 += av[2] * vf[j * 4 + 2];
                    a3 += av[3] * vf[j * 4 + 3];
                }
                pk.u[dd] = f2bf((a0 + a1) + (a2 + a3));
            }
            reinterpret_cast<bf16x8*>(orow)[dq] = pk.v;
        }
    }
}

// ---------------------------------------------------------------------------
// proj GEMM: out[M][512] = out_t(bf16)[M][512] @ Pt[512][512]^T + proj_b (fp32 out)
// ---------------------------------------------------------------------------
__global__ __launch_bounds__(256) void gemm_proj_kernel(
        const uint16_t* __restrict__ At, const uint16_t* __restrict__ Pt,
        const float* __restrict__ proj_b, float* __restrict__ outp) {
    __shared__ uint16_t As[128][72];
    __shared__ uint16_t Bs[128][72];
    const int bx = blockIdx.x;
    const int tn = bx & 3, tm = bx >> 2;
    const int gm = tm * 128, gn = tn * 128;
    const int t = threadIdx.x;
    const int lane = t & 63, w = t >> 6;
    const int wm = w >> 1, wn = w & 1;
    const int l15 = lane & 15, lg = lane >> 4;
    fx4 acc[4][4] = {};
    const int srow = t >> 1, sseg = (t & 1) * 32;
    for (int k0 = 0; k0 < 512; k0 += 64) {
        __syncthreads();
        {
            const uint16_t* srcA = At + (size_t)(gm + srow) * 512 + (k0 + sseg);
            uint16_t* dstA = &As[srow][sseg];
            #pragma unroll
            for (int j = 0; j < 4; j++)
                reinterpret_cast<bf16x8*>(dstA)[j] = reinterpret_cast<const bf16x8*>(srcA)[j];
            const uint16_t* srcB = Pt + (size_t)(gn + srow) * 512 + (k0 + sseg);
            uint16_t* dstB = &Bs[srow][sseg];
            #pragma unroll
            for (int j = 0; j < 4; j++)
                reinterpret_cast<bf16x8*>(dstB)[j] = reinterpret_cast<const bf16x8*>(srcB)[j];
        }
        __syncthreads();
        #pragma unroll
        for (int ks = 0; ks < 2; ks++) {
            const int kof = ks * 32 + lg * 8;
            bf16x8 af[4], bfr[4];
            #pragma unroll
            for (int m = 0; m < 4; m++)
                af[m] = *reinterpret_cast<const bf16x8*>(&As[wm * 64 + m * 16 + l15][kof]);
            #pragma unroll
            for (int n = 0; n < 4; n++)
                bfr[n] = *reinterpret_cast<const bf16x8*>(&Bs[wn * 64 + n * 16 + l15][kof]);
            #pragma unroll
            for (int m = 0; m < 4; m++)
                #pragma unroll
                for (int n = 0; n < 4; n++)
                    acc[m][n] = __builtin_amdgcn_mfma_f32_16x16x32_bf16(
                        af[m], bfr[n], acc[m][n], 0, 0, 0);
        }
    }
    #pragma unroll
    for (int m = 0; m < 4; m++) {
        #pragma unroll
        for (int n = 0; n < 4; n++) {
            const int col = gn + wn * 64 + n * 16 + l15;
            const float bias = proj_b[col];
            #pragma unroll
            for (int r = 0; r < 4; r++) {
                const int row = gm + wm * 64 + m * 16 + lg * 4 + r;
                outp[(size_t)row * CDIM + col] = acc[m][n][r] + bias;
            }
        }
    }
}

// ---------------------------------------------------------------------------
// launch. ws layout (bytes):
//   0         Wt     (1536*512*2 = 1572864)
//   1572864   Pt     ( 512*512*2 =  524288)
//   2097152   Sq     (128*64*4   =   32768)   -- zeroed by prep
//   2129920   Sk     (128*64*4   =   32768)   -- zeroed by prep
//   2162688   G      (128*4096*4 = 2097152)   -- zeroed by prep
//   4259840   attn   (128*4096*4 = 2097152)
//   6356992   qkv    (65536*1536*2 = 201326592)
//   207683584 out_t  (65536*512*2  =  67108864)
//   total 274792448 bytes (~262 MB)
// ---------------------------------------------------------------------------
extern "C" void kernel_launch(void* const* d_in, const int* in_sizes, int n_in,
                              void* d_out, int out_size, void* d_ws, size_t ws_size,
                              hipStream_t stream) {
    const float* x      = (const float*)d_in[0];
    const float* qkv_w  = (const float*)d_in[1];
    const float* q_bias = (const float*)d_in[2];
    const float* v_bias = (const float*)d_in[3];
    const float* scale  = (const float*)d_in[4];
    const float* proj_w = (const float*)d_in[5];
    const float* proj_b = (const float*)d_in[6];
    float* out = (float*)d_out;

    char* w = (char*)d_ws;
    uint16_t* Wt   = (uint16_t*)(w);
    uint16_t* Pt   = (uint16_t*)(w + 1572864);
    float*    Sq   = (float*)   (w + 2097152);
    float*    Sk   = (float*)   (w + 2129920);
    float*    G    = (float*)   (w + 2162688);
    float*    attn = (float*)   (w + 4259840);
    uint16_t* qkv  = (uint16_t*)(w + 6356992);
    uint16_t* out_t= (uint16_t*)(w + 207683584);
    float*    zbase= Sq;  // Sq,Sk,G are contiguous

    hipLaunchKernelGGL(prep_kernel, dim3(1024), dim3(256), 0, stream,
                       qkv_w, proj_w, Wt, Pt, zbase);
    hipLaunchKernelGGL(gemm_qkv_kernel, dim3(6144), dim3(256), 0, stream,
                       x, Wt, q_bias, v_bias, qkv);
    hipLaunchKernelGGL(sumsq_kernel, dim3(512), dim3(256), 0, stream,
                       qkv, Sq, Sk);
    hipLaunchKernelGGL(attn_partial_kernel, dim3(1024), dim3(256), 0, stream,
                       qkv, G);
    hipLaunchKernelGGL(attn_finalize_kernel, dim3(128), dim3(64), 0, stream,
                       G, Sq, Sk, scale, attn);
    hipLaunchKernelGGL(pv_kernel, dim3(1024), dim3(256), 0, stream,
                       qkv, attn, out_t);
    hipLaunchKernelGGL(gemm_proj_kernel, dim3(2048), dim3(256), 0, stream,
                       out_t, Pt, proj_b, out);
}

// Round 2
// 633.065 us; speedup vs baseline: 1.5163x; 1.5163x over previous
//
#include <hip/hip_runtime.h>
#include <stdint.h>
#include <stddef.h>

#define BATCH  16
#define HEADS  8
#define NTOK   4096      // H*W
#define CDIM   512
#define FDIM   1536      // 3*C

typedef short bf16x8 __attribute__((ext_vector_type(8)));
typedef float fx4    __attribute__((ext_vector_type(4)));

__device__ __forceinline__ uint16_t f2bf(float f) {
    uint32_t u = __float_as_uint(f);
    return (uint16_t)((u + 0x7FFFu + ((u >> 16) & 1u)) >> 16); // RNE
}
__device__ __forceinline__ float bf2f(uint16_t u) {
    return __uint_as_float(((uint32_t)u) << 16);
}
// async global->LDS, 16B per lane. LDS dest must be wave-uniform base + lane*16.
__device__ __forceinline__ void gload16(const uint16_t* g, uint16_t* l) {
    __builtin_amdgcn_global_load_lds(
        (const __attribute__((address_space(1))) uint32_t*)(g),
        (__attribute__((address_space(3))) uint32_t*)(l), 16, 0, 0);
}

// ---------------------------------------------------------------------------
// prep: Xb = bf16(x); Wt[f][c] = bf16(qkv_w[c][f]); Pt[f][c] = bf16(proj_w[c][f]);
//       zero Sq/Sk (contiguous 16384 floats)
// ---------------------------------------------------------------------------
__global__ void prep_kernel(const float* __restrict__ X,
                            const float* __restrict__ qkv_w,
                            const float* __restrict__ proj_w,
                            uint16_t* __restrict__ Xb,
                            uint16_t* __restrict__ Wt, uint16_t* __restrict__ Pt,
                            float* __restrict__ Sqk) {
    const int tid = blockIdx.x * blockDim.x + threadIdx.x;
    const int stride = gridDim.x * blockDim.x;
    // Xb: 65536*512 elements in groups of 8
    for (int i = tid; i < (1 << 22); i += stride) {
        const fx4* src = reinterpret_cast<const fx4*>(X + (size_t)i * 8);
        fx4 v0 = src[0], v1 = src[1];
        union { bf16x8 v; uint16_t u[8]; } pk;
        #pragma unroll
        for (int e = 0; e < 4; e++) { pk.u[e] = f2bf(v0[e]); pk.u[4 + e] = f2bf(v1[e]); }
        reinterpret_cast<bf16x8*>(Xb)[i] = pk.v;
    }
    for (int i = tid; i < FDIM * CDIM; i += stride) {
        int f = i >> 9, c = i & 511;
        Wt[i] = f2bf(qkv_w[(size_t)c * FDIM + f]);
    }
    for (int i = tid; i < CDIM * CDIM; i += stride) {
        int f = i >> 9, c = i & 511;
        Pt[i] = f2bf(proj_w[(size_t)c * CDIM + f]);
    }
    for (int i = tid; i < 16384; i += stride) Sqk[i] = 0.0f;
}

// ---------------------------------------------------------------------------
// qkv GEMM (m97 structure): qkv[M][1536] = Xb[M][512] @ Wt[1536][512]^T + bias
// 128x128 tile, BK=64, linear LDS, global_load_lds(16), XCD-swizzled grid.
// ---------------------------------------------------------------------------
__global__ __launch_bounds__(256) void gemm_qkv_kernel(
        const uint16_t* __restrict__ Xb, const uint16_t* __restrict__ Wt,
        const float* __restrict__ q_bias, const float* __restrict__ v_bias,
        uint16_t* __restrict__ qkv) {
    __shared__ uint16_t As[128 * 64];
    __shared__ uint16_t Bs[128 * 64];
    const int bx = blockIdx.x;
    const int swz = (bx & 7) * 768 + (bx >> 3);   // nwg=6144 = 8*768, bijective
    const int tm = swz / 12, tn = swz % 12;       // tn fastest: A-tile reuse in-XCD
    const int gm = tm * 128, gn = tn * 128;
    const int t = threadIdx.x, lane = t & 63, w = t >> 6;
    const int wm = w >> 1, wn = w & 1;
    const int l15 = lane & 15, lg = lane >> 4;
    fx4 acc[4][4] = {};
    const int srow = t >> 3;            // 0..31 (each j adds 32 rows)
    const int scol = (t & 7) * 8;       // element col within BK=64
    for (int k0 = 0; k0 < 512; k0 += 64) {
        const uint16_t* ga = Xb + (size_t)(gm + srow) * 512 + k0 + scol;
        const uint16_t* gb = Wt + (size_t)(gn + srow) * 512 + k0 + scol;
        uint16_t* la = &As[t * 8];
        uint16_t* lb = &Bs[t * 8];
        #pragma unroll
        for (int j = 0; j < 4; j++) {
            gload16(ga + (size_t)j * 32 * 512, la + j * 2048);
            gload16(gb + (size_t)j * 32 * 512, lb + j * 2048);
        }
        __syncthreads();   // drains vmcnt(0): tile resident
        #pragma unroll
        for (int ks = 0; ks < 2; ks++) {
            const int kof = ks * 32 + lg * 8;
            bf16x8 af[4], bfr[4];
            #pragma unroll
            for (int m = 0; m < 4; m++)
                af[m] = *reinterpret_cast<const bf16x8*>(&As[(wm * 64 + m * 16 + l15) * 64 + kof]);
            #pragma unroll
            for (int n = 0; n < 4; n++)
                bfr[n] = *reinterpret_cast<const bf16x8*>(&Bs[(wn * 64 + n * 16 + l15) * 64 + kof]);
            #pragma unroll
            for (int m = 0; m < 4; m++)
                #pragma unroll
                for (int n = 0; n < 4; n++)
                    acc[m][n] = __builtin_amdgcn_mfma_f32_16x16x32_bf16(
                        af[m], bfr[n], acc[m][n], 0, 0, 0);
        }
        __syncthreads();   // all waves done reading before next overwrite
    }
    #pragma unroll
    for (int m = 0; m < 4; m++) {
        #pragma unroll
        for (int n = 0; n < 4; n++) {
            const int col = gn + wn * 64 + n * 16 + l15;
            const float bias = (col < 512) ? q_bias[col]
                              : ((col < 1024) ? 0.0f : v_bias[col - 1024]);
            #pragma unroll
            for (int r = 0; r < 4; r++) {
                const int row = gm + wm * 64 + m * 16 + lg * 4 + r;
                qkv[(size_t)row * FDIM + col] = f2bf(acc[m][n][r] + bias);
            }
        }
    }
}

// ---------------------------------------------------------------------------
// attn_qk: Gpart[quarter][bh][d][e] = sum_{n in quarter} q[n,d]*k[n,e]  (MFMA)
// + fused sumsq: Sq[bh][d] += sum q^2, Sk likewise (atomic).
// grid = 512 (bh,quarter); 4 waves each own a 32x32 quadrant of G.
// q,k tiles staged TRANSPOSED in LDS ([ch][tok], pad 72) so MFMA K-dim = token.
// ---------------------------------------------------------------------------
__global__ __launch_bounds__(256) void attn_qk_kernel(
        const uint16_t* __restrict__ qkv, float* __restrict__ Gpart,
        float* __restrict__ Sq, float* __restrict__ Sk) {
    const int blk = blockIdx.x;
    const int bh = blk >> 2, quarter = blk & 3;
    const int b = bh >> 3, h = bh & 7;
    const int t = threadIdx.x, lane = t & 63, w = t >> 6;
    const int l15 = lane & 15, lg = lane >> 4;
    const int wr = w >> 1, wc = w & 1;
    __shared__ uint16_t qT[64][72];
    __shared__ uint16_t kT[64][72];
    const int tok = t >> 2, chgrp = t & 3, ch0 = chgrp * 16;
    const uint16_t* base = qkv + (size_t)b * NTOK * FDIM + h * 192;
    fx4 acc[2][2] = {};
    float sq[16] = {}, sk[16] = {};
    for (int tile = 0; tile < 16; tile++) {
        const int n = quarter * 1024 + tile * 64 + tok;
        const uint16_t* row = base + (size_t)n * FDIM;
        union { bf16x8 v; uint16_t u[8]; } qa, qb, ka, kb;
        qa.v = *reinterpret_cast<const bf16x8*>(row + ch0);
        qb.v = *reinterpret_cast<const bf16x8*>(row + ch0 + 8);
        ka.v = *reinterpret_cast<const bf16x8*>(row + 64 + ch0);
        kb.v = *reinterpret_cast<const bf16x8*>(row + 64 + ch0 + 8);
        __syncthreads();   // previous tile's compute done
        #pragma unroll
        for (int j = 0; j < 8; j++) {
            qT[ch0 + j][tok] = qa.u[j];
            qT[ch0 + 8 + j][tok] = qb.u[j];
            kT[ch0 + j][tok] = ka.u[j];
            kT[ch0 + 8 + j][tok] = kb.u[j];
            float f0 = bf2f(qa.u[j]), f1 = bf2f(qb.u[j]);
            float g0 = bf2f(ka.u[j]), g1 = bf2f(kb.u[j]);
            sq[j] += f0 * f0; sq[8 + j] += f1 * f1;
            sk[j] += g0 * g0; sk[8 + j] += g1 * g1;
        }
        __syncthreads();   // tile staged
        #pragma unroll
        for (int ks = 0; ks < 2; ks++) {
            const int kof = ks * 32 + lg * 8;
            bf16x8 a0 = *reinterpret_cast<const bf16x8*>(&qT[wr * 32 + l15][kof]);
            bf16x8 a1 = *reinterpret_cast<const bf16x8*>(&qT[wr * 32 + 16 + l15][kof]);
            bf16x8 b0 = *reinterpret_cast<const bf16x8*>(&kT[wc * 32 + l15][kof]);
            bf16x8 b1 = *reinterpret_cast<const bf16x8*>(&kT[wc * 32 + 16 + l15][kof]);
            acc[0][0] = __builtin_amdgcn_mfma_f32_16x16x32_bf16(a0, b0, acc[0][0], 0, 0, 0);
            acc[0][1] = __builtin_amdgcn_mfma_f32_16x16x32_bf16(a0, b1, acc[0][1], 0, 0, 0);
            acc[1][0] = __builtin_amdgcn_mfma_f32_16x16x32_bf16(a1, b0, acc[1][0], 0, 0, 0);
            acc[1][1] = __builtin_amdgcn_mfma_f32_16x16x32_bf16(a1, b1, acc[1][1], 0, 0, 0);
        }
    }
    // sumsq: reduce across lanes sharing chgrp (stride-4 lanes), then atomic
    #pragma unroll
    for (int off = 4; off <= 32; off <<= 1) {
        #pragma unroll
        for (int j = 0; j < 16; j++) {
            sq[j] += __shfl_xor(sq[j], off, 64);
            sk[j] += __shfl_xor(sk[j], off, 64);
        }
    }
    if (lane < 4) {   // lane == its chgrp
        #pragma unroll
        for (int j = 0; j < 16; j++) {
            atomicAdd(&Sq[bh * 64 + lane * 16 + j], sq[j]);
            atomicAdd(&Sk[bh * 64 + lane * 16 + j], sk[j]);
        }
    }
    float* gp = Gpart + (size_t)quarter * 524288 + (size_t)bh * 4096;
    #pragma unroll
    for (int mi = 0; mi < 2; mi++)
        #pragma unroll
        for (int ni = 0; ni < 2; ni++)
            #pragma unroll
            for (int r = 0; r < 4; r++) {
                const int d = wr * 32 + mi * 16 + lg * 4 + r;
                const int e = wc * 32 + ni * 16 + l15;
                gp[d * 64 + e] = acc[mi][ni][r];
            }
}

// ---------------------------------------------------------------------------
// finalize: attnb[bh][d][e] = bf16( softmax_e( exp(scale_h)*G*rq[d]*rk[e] ) )
// 4 waves per bh, each wave handles 16 d-rows; lane = e.
// ---------------------------------------------------------------------------
__global__ void attn_finalize_kernel(const float* __restrict__ Gpart,
                                     const float* __restrict__ Sq,
                                     const float* __restrict__ Sk,
                                     const float* __restrict__ scale,
                                     uint16_t* __restrict__ attnb) {
    const int bh = blockIdx.x;
    const int h = bh & 7;
    const int t = threadIdx.x;           // 256
    const int e = t & 63, w = t >> 6;
    const float es = expf(scale[h]);
    const float rk = rsqrtf(fmaxf(Sk[bh * 64 + e], 1.55e-5f));
    const float* g0 = Gpart + (size_t)bh * 4096;
    for (int d = w; d < 64; d += 4) {
        const float rq = rsqrtf(fmaxf(Sq[bh * 64 + d], 1.55e-5f));
        float g = g0[d * 64 + e] + g0[524288 + d * 64 + e]
                + g0[1048576 + d * 64 + e] + g0[1572864 + d * 64 + e];
        float x = es * g * rq * rk;
        float m = x;
        #pragma unroll
        for (int off = 32; off; off >>= 1) m = fmaxf(m, __shfl_xor(m, off, 64));
        float p = expf(x - m);
        float s = p;
        #pragma unroll
        for (int off = 32; off; off >>= 1) s += __shfl_xor(s, off, 64);
        attnb[(size_t)bh * 4096 + d * 64 + e] = f2bf(p / s);
    }
}

// ---------------------------------------------------------------------------
// pv (MFMA): out_t[n][h*64+d] = sum_e attnb[bh][d][e] * v[n][e]
// grid = 8192 (bh, 64-token chunk). v natural A-operand, attnb natural B.
// ---------------------------------------------------------------------------
__global__ __launch_bounds__(256) void pv_kernel(
        const uint16_t* __restrict__ qkv, const uint16_t* __restrict__ attnb,
        uint16_t* __restrict__ out_t) {
    const int blk = blockIdx.x;
    const int bh = blk >> 6, chunk = blk & 63;
    const int b = bh >> 3, h = bh & 7;
    const int n0 = chunk * 64;
    const int t = threadIdx.x, lane = t & 63, w = t >> 6;
    const int l15 = lane & 15, lg = lane >> 4;
    __shared__ uint16_t Vs[64][72];
    {   // stage V tile [64 tok][64 ch]
        const int tok = t >> 2, seg = (t & 3) * 16;
        const uint16_t* vrow = qkv + (size_t)(b * NTOK + n0 + tok) * FDIM + h * 192 + 128 + seg;
        *reinterpret_cast<bf16x8*>(&Vs[tok][seg])     = *reinterpret_cast<const bf16x8*>(vrow);
        *reinterpret_cast<bf16x8*>(&Vs[tok][seg + 8]) = *reinterpret_cast<const bf16x8*>(vrow + 8);
    }
    // B-frags from global (L2-hot, 8 KB per bh)
    bf16x8 bfr[4][2];
    const uint16_t* ab = attnb + (size_t)bh * 4096;
    #pragma unroll
    for (int n = 0; n < 4; n++)
        #pragma unroll
        for (int ks = 0; ks < 2; ks++)
            bfr[n][ks] = *reinterpret_cast<const bf16x8*>(ab + (n * 16 + l15) * 64 + ks * 32 + lg * 8);
    __syncthreads();
    fx4 acc[4] = {};
    #pragma unroll
    for (int ks = 0; ks < 2; ks++) {
        const int kof = ks * 32 + lg * 8;
        bf16x8 a = *reinterpret_cast<const bf16x8*>(&Vs[w * 16 + l15][kof]);
        #pragma unroll
        for (int n = 0; n < 4; n++)
            acc[n] = __builtin_amdgcn_mfma_f32_16x16x32_bf16(a, bfr[n][ks], acc[n], 0, 0, 0);
    }
    #pragma unroll
    for (int n = 0; n < 4; n++)
        #pragma unroll
        for (int r = 0; r < 4; r++) {
            const int tokg = b * NTOK + n0 + w * 16 + lg * 4 + r;
            out_t[(size_t)tokg * CDIM + h * 64 + n * 16 + l15] = f2bf(acc[n][r]);
        }
}

// ---------------------------------------------------------------------------
// proj GEMM (m97 structure): out[M][512] = out_t[M][512] @ Pt[512][512]^T + proj_b
// ---------------------------------------------------------------------------
__global__ __launch_bounds__(256) void gemm_proj_kernel(
        const uint16_t* __restrict__ At, const uint16_t* __restrict__ Pt,
        const float* __restrict__ proj_b, float* __restrict__ outp) {
    __shared__ uint16_t As[128 * 64];
    __shared__ uint16_t Bs[128 * 64];
    const int bx = blockIdx.x;
    const int swz = (bx & 7) * 256 + (bx >> 3);   // nwg=2048 = 8*256, bijective
    const int tn = swz & 3, tm = swz >> 2;
    const int gm = tm * 128, gn = tn * 128;
    const int t = threadIdx.x, lane = t & 63, w = t >> 6;
    const int wm = w >> 1, wn = w & 1;
    const int l15 = lane & 15, lg = lane >> 4;
    fx4 acc[4][4] = {};
    const int srow = t >> 3;
    const int scol = (t & 7) * 8;
    for (int k0 = 0; k0 < 512; k0 += 64) {
        const uint16_t* ga = At + (size_t)(gm + srow) * 512 + k0 + scol;
        const uint16_t* gb = Pt + (size_t)(gn + srow) * 512 + k0 + scol;
        uint16_t* la = &As[t * 8];
        uint16_t* lb = &Bs[t * 8];
        #pragma unroll
        for (int j = 0; j < 4; j++) {
            gload16(ga + (size_t)j * 32 * 512, la + j * 2048);
            gload16(gb + (size_t)j * 32 * 512, lb + j * 2048);
        }
        __syncthreads();
        #pragma unroll
        for (int ks = 0; ks < 2; ks++) {
            const int kof = ks * 32 + lg * 8;
            bf16x8 af[4], bfr[4];
            #pragma unroll
            for (int m = 0; m < 4; m++)
                af[m] = *reinterpret_cast<const bf16x8*>(&As[(wm * 64 + m * 16 + l15) * 64 + kof]);
            #pragma unroll
            for (int n = 0; n < 4; n++)
                bfr[n] = *reinterpret_cast<const bf16x8*>(&Bs[(wn * 64 + n * 16 + l15) * 64 + kof]);
            #pragma unroll
            for (int m = 0; m < 4; m++)
                #pragma unroll
                for (int n = 0; n < 4; n++)
                    acc[m][n] = __builtin_amdgcn_mfma_f32_16x16x32_bf16(
                        af[m], bfr[n], acc[m][n], 0, 0, 0);
        }
        __syncthreads();
    }
    #pragma unroll
    for (int m = 0; m < 4; m++) {
        #pragma unroll
        for (int n = 0; n < 4; n++) {
            const int col = gn + wn * 64 + n * 16 + l15;
            const float bias = proj_b[col];
            #pragma unroll
            for (int r = 0; r < 4; r++) {
                const int row = gm + wm * 64 + m * 16 + lg * 4 + r;
                outp[(size_t)row * CDIM + col] = acc[m][n][r] + bias;
            }
        }
    }
}

// ---------------------------------------------------------------------------
// ws layout (bytes):
//   0          Wt      1572864
//   1572864    Pt       524288
//   2097152    Sq        32768   (zeroed by prep, with Sk: 16384 floats)
//   2129920    Sk        32768
//   2162688    Gpart   8388608   (4 quarters x 128 bh x 4096)
//   10551296   attnb   1048576   (bf16)
//   11599872   qkv   201326592
//   212926464  Xb/out_t 67108864 (aliased: Xb dead after gemm_qkv; out_t born in pv)
//   total 280035328 (~267 MB)
// ---------------------------------------------------------------------------
extern "C" void kernel_launch(void* const* d_in, const int* in_sizes, int n_in,
                              void* d_out, int out_size, void* d_ws, size_t ws_size,
                              hipStream_t stream) {
    (void)in_sizes; (void)n_in; (void)out_size; (void)ws_size;
    const float* x      = (const float*)d_in[0];
    const float* qkv_w  = (const float*)d_in[1];
    const float* q_bias = (const float*)d_in[2];
    const float* v_bias = (const float*)d_in[3];
    const float* scale  = (const float*)d_in[4];
    const float* proj_w = (const float*)d_in[5];
    const float* proj_b = (const float*)d_in[6];
    float* out = (float*)d_out;

    char* wsp = (char*)d_ws;
    uint16_t* Wt    = (uint16_t*)(wsp);
    uint16_t* Pt    = (uint16_t*)(wsp + 1572864);
    float*    Sq    = (float*)   (wsp + 2097152);
    float*    Sk    = (float*)   (wsp + 2129920);
    float*    Gpart = (float*)   (wsp + 2162688);
    uint16_t* attnb = (uint16_t*)(wsp + 10551296);
    uint16_t* qkv   = (uint16_t*)(wsp + 11599872);
    uint16_t* Xb    = (uint16_t*)(wsp + 212926464);
    uint16_t* out_t = Xb;   // disjoint lifetime alias

    hipLaunchKernelGGL(prep_kernel, dim3(2048), dim3(256), 0, stream,
                       x, qkv_w, proj_w, Xb, Wt, Pt, Sq);
    hipLaunchKernelGGL(gemm_qkv_kernel, dim3(6144), dim3(256), 0, stream,
                       Xb, Wt, q_bias, v_bias, qkv);
    hipLaunchKernelGGL(attn_qk_kernel, dim3(512), dim3(256), 0, stream,
                       qkv, Gpart, Sq, Sk);
    hipLaunchKernelGGL(attn_finalize_kernel, dim3(128), dim3(256), 0, stream,
                       Gpart, Sq, Sk, scale, attnb);
    hipLaunchKernelGGL(pv_kernel, dim3(8192), dim3(256), 0, stream,
                       qkv, attnb, out_t);
    hipLaunchKernelGGL(gemm_proj_kernel, dim3(2048), dim3(256), 0, stream,
                       out_t, Pt, proj_b, out);
}

// Round 3
// 578.528 us; speedup vs baseline: 1.6593x; 1.0943x over previous
//
#include <hip/hip_runtime.h>
#include <stdint.h>
#include <stddef.h>

#define BATCH  16
#define HEADS  8
#define NTOK   4096      // H*W
#define CDIM   512
#define FDIM   1536      // 3*C

typedef short bf16x8 __attribute__((ext_vector_type(8)));
typedef float fx4    __attribute__((ext_vector_type(4)));

__device__ __forceinline__ uint16_t f2bf(float f) {
    uint32_t u = __float_as_uint(f);
    return (uint16_t)((u + 0x7FFFu + ((u >> 16) & 1u)) >> 16); // RNE
}
__device__ __forceinline__ float bf2f(uint16_t u) {
    return __uint_as_float(((uint32_t)u) << 16);
}
// async global->LDS, 16B per lane. LDS dest must be wave-uniform base + lane*16.
__device__ __forceinline__ void gload16(const uint16_t* g, uint16_t* l) {
    __builtin_amdgcn_global_load_lds(
        (const __attribute__((address_space(1))) uint32_t*)(g),
        (__attribute__((address_space(3))) uint32_t*)(l), 16, 0, 0);
}
// XOR-swizzled index into a [R][128] u16 LDS tile (byte ^= (row&7)<<4)
__device__ __forceinline__ int cidx(int row, int col) {
    return row * 128 + (col ^ ((row & 7) << 3));
}

// ---------------------------------------------------------------------------
// transpose_w: Wt[f][c] = bf16(qkv_w[c][f]); Pt[f][c] = bf16(proj_w[c][f])
// coalesced via 32x32 LDS tiles. grid = 768 + 256 blocks.
// ---------------------------------------------------------------------------
__global__ void transpose_w_kernel(const float* __restrict__ qkv_w,
                                   const float* __restrict__ proj_w,
                                   uint16_t* __restrict__ Wt,
                                   uint16_t* __restrict__ Pt) {
    __shared__ uint16_t tile[32][33];
    int blk = blockIdx.x;
    const float* src; uint16_t* dst; int W, Hh, r0, c0;
    if (blk < 768) {                    // qkv_w: 512 x 1536
        int tr = blk / 48, tc = blk % 48;
        src = qkv_w; dst = Wt; W = 1536; Hh = 512; r0 = tr * 32; c0 = tc * 32;
    } else {                            // proj_w: 512 x 512
        blk -= 768;
        int tr = blk / 16, tc = blk % 16;
        src = proj_w; dst = Pt; W = 512; Hh = 512; r0 = tr * 32; c0 = tc * 32;
    }
    const int tx = threadIdx.x & 31, ty = threadIdx.x >> 5;   // 32 x 8
    #pragma unroll
    for (int j = 0; j < 4; j++)
        tile[ty + 8 * j][tx] = f2bf(src[(size_t)(r0 + ty + 8 * j) * W + c0 + tx]);
    __syncthreads();
    #pragma unroll
    for (int j = 0; j < 4; j++)
        dst[(size_t)(c0 + ty + 8 * j) * Hh + r0 + tx] = tile[tx][ty + 8 * j];
}

// ---------------------------------------------------------------------------
// prep: Xb = bf16(x); zero Sq/Sk (16384 contiguous floats at Sq)
// ---------------------------------------------------------------------------
__global__ void prep_kernel(const float* __restrict__ X,
                            uint16_t* __restrict__ Xb,
                            float* __restrict__ Sqk) {
    const int tid = blockIdx.x * blockDim.x + threadIdx.x;
    const int stride = gridDim.x * blockDim.x;
    for (int i = tid; i < (1 << 22); i += stride) {
        const fx4* src = reinterpret_cast<const fx4*>(X + (size_t)i * 8);
        fx4 v0 = src[0], v1 = src[1];
        union { bf16x8 v; uint16_t u[8]; } pk;
        #pragma unroll
        for (int e = 0; e < 4; e++) { pk.u[e] = f2bf(v0[e]); pk.u[4 + e] = f2bf(v1[e]); }
        reinterpret_cast<bf16x8*>(Xb)[i] = pk.v;
    }
    for (int i = tid; i < 16384; i += stride) Sqk[i] = 0.0f;
}

// ---------------------------------------------------------------------------
// qkv GEMM + layout-split epilogue + fused sumsq.
// C-tile staged in swizzled LDS; q,k emitted transposed to QT/KT[bh][d][tok];
// v emitted to VT[token][c]. Sq/Sk accumulated from the q/k column reads.
// ---------------------------------------------------------------------------
__global__ __launch_bounds__(256) void gemm_qkv_kernel(
        const uint16_t* __restrict__ Xb, const uint16_t* __restrict__ Wt,
        const float* __restrict__ q_bias, const float* __restrict__ v_bias,
        uint16_t* __restrict__ QT, uint16_t* __restrict__ KT,
        uint16_t* __restrict__ VT,
        float* __restrict__ Sq, float* __restrict__ Sk) {
    __shared__ uint16_t sh[128 * 128];          // 32 KB: As|Bs during loop, Cs after
    uint16_t* As = sh;
    uint16_t* Bs = sh + 8192;
    const int bx = blockIdx.x;
    const int swz = (bx & 7) * 768 + (bx >> 3); // nwg=6144, bijective XCD swizzle
    const int tm = swz / 12, tn = swz % 12;
    const int gm = tm * 128, gn = tn * 128;
    const int b = gm >> 12, tok0 = gm & 4095;
    const int t = threadIdx.x, lane = t & 63, w = t >> 6;
    const int wm = w >> 1, wn = w & 1;
    const int l15 = lane & 15, lg = lane >> 4;
    fx4 acc[4][4] = {};
    const int skey = (t >> 3) & 7;                       // row&7 for this lane's stage rows
    const int scol0 = ((t & 7) ^ skey) * 8;              // pre-swizzled source col
    for (int k0 = 0; k0 < 512; k0 += 64) {
        const uint16_t* ga = Xb + (size_t)(gm + (t >> 3)) * 512 + k0 + scol0;
        const uint16_t* gb = Wt + (size_t)(gn + (t >> 3)) * 512 + k0 + scol0;
        uint16_t* la = &As[t * 8];
        uint16_t* lb = &Bs[t * 8];
        #pragma unroll
        for (int j = 0; j < 4; j++) {
            gload16(ga + (size_t)j * 32 * 512, la + j * 2048);
            gload16(gb + (size_t)j * 32 * 512, lb + j * 2048);
        }
        __syncthreads();
        #pragma unroll
        for (int ks = 0; ks < 2; ks++) {
            const int kof = ks * 32 + lg * 8;
            bf16x8 af[4], bfr[4];
            #pragma unroll
            for (int m = 0; m < 4; m++) {
                const int row = wm * 64 + m * 16 + l15;
                af[m] = *reinterpret_cast<const bf16x8*>(&As[row * 64 + (kof ^ ((row & 7) << 3))]);
            }
            #pragma unroll
            for (int n = 0; n < 4; n++) {
                const int row = wn * 64 + n * 16 + l15;
                bfr[n] = *reinterpret_cast<const bf16x8*>(&Bs[row * 64 + (kof ^ ((row & 7) << 3))]);
            }
            #pragma unroll
            for (int m = 0; m < 4; m++)
                #pragma unroll
                for (int n = 0; n < 4; n++)
                    acc[m][n] = __builtin_amdgcn_mfma_f32_16x16x32_bf16(
                        af[m], bfr[n], acc[m][n], 0, 0, 0);
        }
        __syncthreads();
    }
    // ---- stage C tile (bias fused) into swizzled LDS ----
    #pragma unroll
    for (int n = 0; n < 4; n++) {
        const int col = gn + wn * 64 + n * 16 + l15;
        const float bias = (col < 512) ? q_bias[col]
                          : ((col < 1024) ? 0.0f : v_bias[col - 1024]);
        #pragma unroll
        for (int m = 0; m < 4; m++)
            #pragma unroll
            for (int r = 0; r < 4; r++) {
                const int lrow = wm * 64 + m * 16 + lg * 4 + r;
                const int lcol = wn * 64 + n * 16 + l15;
                sh[cidx(lrow, lcol)] = f2bf(acc[m][n][r] + bias);
            }
    }
    __syncthreads();
    // ---- layout-split write: 2 chunks of 64 cols ----
    const int cc = t >> 7, tloc = t & 127;
    const int u = (gn >> 6) + cc;
    const int h = u / 3, which = u % 3;
    const int bh = b * 8 + h;
    if (which < 2) {   // q or k -> [bh][d][tok] + sumsq
        const int d = tloc & 63, oct = tloc >> 6;
        uint16_t* dst = (which == 0 ? QT : KT)
                        + ((size_t)bh * 64 + d) * 4096 + tok0 + oct * 64;
        float ss = 0.f;
        #pragma unroll
        for (int g = 0; g < 8; g++) {
            union { bf16x8 v; uint16_t u16v[8]; } pk;
            #pragma unroll
            for (int s2 = 0; s2 < 8; s2++) {
                uint16_t val = sh[cidx(oct * 64 + g * 8 + s2, cc * 64 + d)];
                pk.u16v[s2] = val;
                float f = bf2f(val);
                ss += f * f;
            }
            *reinterpret_cast<bf16x8*>(dst + g * 8) = pk.v;
        }
        atomicAdd((which == 0 ? Sq : Sk) + bh * 64 + d, ss);
    } else {           // v -> VT[token][h*64+e]
        const int tok = tloc;
        uint16_t* dst = VT + (size_t)(gm + tok) * 512 + h * 64;
        #pragma unroll
        for (int bb = 0; bb < 8; bb++) {
            bf16x8 v = *reinterpret_cast<const bf16x8*>(&sh[cidx(tok, cc * 64 + bb * 8)]);
            *reinterpret_cast<bf16x8*>(dst + bb * 8) = v;
        }
    }
}

// ---------------------------------------------------------------------------
// attn_qk: Gpart[quarter][bh][d][e] = sum_{n in quarter} q[d,n]*k[e,n]
// pure m97-style: gload_lds QT/KT tiles (pre-swizzled source), MFMA, no ds_write.
// grid = 512 (bh x quarter), 4 waves own 32x32 quadrants.
// ---------------------------------------------------------------------------
__global__ __launch_bounds__(256) void attn_qk_kernel(
        const uint16_t* __restrict__ QT, const uint16_t* __restrict__ KT,
        float* __restrict__ Gpart) {
    __shared__ uint16_t Qs[64 * 128];   // 16 KB each, linear (swizzled via source)
    __shared__ uint16_t Ks[64 * 128];
    const int blk = blockIdx.x;
    const int bh = blk >> 2, quarter = blk & 3;
    const int t = threadIdx.x, lane = t & 63, w = t >> 6;
    const int l15 = lane & 15, lg = lane >> 4;
    const int wr = w >> 1, wc = w & 1;
    fx4 acc[2][2] = {};
    const uint16_t* qbase = QT + (size_t)bh * 64 * 4096;
    const uint16_t* kbase = KT + (size_t)bh * 64 * 4096;
    for (int it = 0; it < 8; it++) {
        const int tokt = quarter * 1024 + it * 128;
        #pragma unroll
        for (int j = 0; j < 4; j++) {
            const int li = j * 256 + t;
            const int row = li >> 4;                    // d row 0..63
            const int src_off = (((li & 15) ^ (row & 7)) << 3);  // pre-swizzled tok offset
            gload16(qbase + (size_t)row * 4096 + tokt + src_off, &Qs[li * 8]);
            gload16(kbase + (size_t)row * 4096 + tokt + src_off, &Ks[li * 8]);
        }
        __syncthreads();
        #pragma unroll
        for (int ks = 0; ks < 4; ks++) {
            const int kof = ks * 32 + lg * 8;
            const int ra0 = wr * 32 + l15,      ra1 = wr * 32 + 16 + l15;
            const int rb0 = wc * 32 + l15,      rb1 = wc * 32 + 16 + l15;
            bf16x8 a0 = *reinterpret_cast<const bf16x8*>(&Qs[ra0 * 128 + (kof ^ ((ra0 & 7) << 3))]);
            bf16x8 a1 = *reinterpret_cast<const bf16x8*>(&Qs[ra1 * 128 + (kof ^ ((ra1 & 7) << 3))]);
            bf16x8 b0 = *reinterpret_cast<const bf16x8*>(&Ks[rb0 * 128 + (kof ^ ((rb0 & 7) << 3))]);
            bf16x8 b1 = *reinterpret_cast<const bf16x8*>(&Ks[rb1 * 128 + (kof ^ ((rb1 & 7) << 3))]);
            acc[0][0] = __builtin_amdgcn_mfma_f32_16x16x32_bf16(a0, b0, acc[0][0], 0, 0, 0);
            acc[0][1] = __builtin_amdgcn_mfma_f32_16x16x32_bf16(a0, b1, acc[0][1], 0, 0, 0);
            acc[1][0] = __builtin_amdgcn_mfma_f32_16x16x32_bf16(a1, b0, acc[1][0], 0, 0, 0);
            acc[1][1] = __builtin_amdgcn_mfma_f32_16x16x32_bf16(a1, b1, acc[1][1], 0, 0, 0);
        }
        __syncthreads();
    }
    float* gp = Gpart + (size_t)quarter * 524288 + (size_t)bh * 4096;
    #pragma unroll
    for (int mi = 0; mi < 2; mi++)
        #pragma unroll
        for (int ni = 0; ni < 2; ni++)
            #pragma unroll
            for (int r = 0; r < 4; r++) {
                const int d = wr * 32 + mi * 16 + lg * 4 + r;
                const int e = wc * 32 + ni * 16 + l15;
                gp[d * 64 + e] = acc[mi][ni][r];
            }
}

// ---------------------------------------------------------------------------
// finalize: attnb[bh][d][e] = bf16( softmax_e( exp(scale_h)*G*rq[d]*rk[e] ) )
// ---------------------------------------------------------------------------
__global__ void attn_finalize_kernel(const float* __restrict__ Gpart,
                                     const float* __restrict__ Sq,
                                     const float* __restrict__ Sk,
                                     const float* __restrict__ scale,
                                     uint16_t* __restrict__ attnb) {
    const int bh = blockIdx.x;
    const int h = bh & 7;
    const int t = threadIdx.x;           // 256
    const int e = t & 63, w = t >> 6;
    const float es = expf(scale[h]);
    const float rk = rsqrtf(fmaxf(Sk[bh * 64 + e], 1.55e-5f));
    const float* g0 = Gpart + (size_t)bh * 4096;
    for (int d = w; d < 64; d += 4) {
        const float rq = rsqrtf(fmaxf(Sq[bh * 64 + d], 1.55e-5f));
        float g = g0[d * 64 + e] + g0[524288 + d * 64 + e]
                + g0[1048576 + d * 64 + e] + g0[1572864 + d * 64 + e];
        float x = es * g * rq * rk;
        float m = x;
        #pragma unroll
        for (int off = 32; off; off >>= 1) m = fmaxf(m, __shfl_xor(m, off, 64));
        float p = expf(x - m);
        float s = p;
        #pragma unroll
        for (int off = 32; off; off >>= 1) s += __shfl_xor(s, off, 64);
        attnb[(size_t)bh * 4096 + d * 64 + e] = f2bf(p / s);
    }
}

// ---------------------------------------------------------------------------
// pv (MFMA): out_t[n][h*64+d] = sum_e attnb[bh][d][e] * v[n][e]
// grid = 8192 (bh, 64-token chunk). V staged via gload_lds (swizzled source).
// ---------------------------------------------------------------------------
__global__ __launch_bounds__(256) void pv_kernel(
        const uint16_t* __restrict__ VT, const uint16_t* __restrict__ attnb,
        uint16_t* __restrict__ out_t) {
    __shared__ uint16_t Vs[64 * 64];   // 8 KB linear
    const int blk = blockIdx.x;
    const int bh = blk >> 6, chunk = blk & 63;
    const int b = bh >> 3, h = bh & 7;
    const int n0 = chunk * 64;
    const int t = threadIdx.x, lane = t & 63, w = t >> 6;
    const int l15 = lane & 15, lg = lane >> 4;
    #pragma unroll
    for (int j = 0; j < 2; j++) {
        const int li = j * 256 + t;
        const int row = li >> 3;                       // token row 0..63
        const int src_off = (((li & 7) ^ (row & 7)) << 3);
        gload16(VT + (size_t)(b * NTOK + n0 + row) * 512 + h * 64 + src_off, &Vs[li * 8]);
    }
    // B-frags from global (L2-hot)
    bf16x8 bfr[4][2];
    const uint16_t* ab = attnb + (size_t)bh * 4096;
    #pragma unroll
    for (int n = 0; n < 4; n++)
        #pragma unroll
        for (int ks = 0; ks < 2; ks++)
            bfr[n][ks] = *reinterpret_cast<const bf16x8*>(ab + (n * 16 + l15) * 64 + ks * 32 + lg * 8);
    __syncthreads();
    fx4 acc[4] = {};
    #pragma unroll
    for (int ks = 0; ks < 2; ks++) {
        const int row = w * 16 + l15;
        const int kof = ks * 32 + lg * 8;
        bf16x8 a = *reinterpret_cast<const bf16x8*>(&Vs[row * 64 + (kof ^ ((row & 7) << 3))]);
        #pragma unroll
        for (int n = 0; n < 4; n++)
            acc[n] = __builtin_amdgcn_mfma_f32_16x16x32_bf16(a, bfr[n][ks], acc[n], 0, 0, 0);
    }
    #pragma unroll
    for (int n = 0; n < 4; n++)
        #pragma unroll
        for (int r = 0; r < 4; r++) {
            const int tokg = b * NTOK + n0 + w * 16 + lg * 4 + r;
            out_t[(size_t)tokg * CDIM + h * 64 + n * 16 + l15] = f2bf(acc[n][r]);
        }
}

// ---------------------------------------------------------------------------
// proj GEMM (m97 + source swizzle): out[M][512] = out_t @ Pt^T + proj_b (fp32)
// ---------------------------------------------------------------------------
__global__ __launch_bounds__(256) void gemm_proj_kernel(
        const uint16_t* __restrict__ At, const uint16_t* __restrict__ Pt,
        const float* __restrict__ proj_b, float* __restrict__ outp) {
    __shared__ uint16_t As[128 * 64];
    __shared__ uint16_t Bs[128 * 64];
    const int bx = blockIdx.x;
    const int swz = (bx & 7) * 256 + (bx >> 3);   // nwg=2048, bijective
    const int tn = swz & 3, tm = swz >> 2;
    const int gm = tm * 128, gn = tn * 128;
    const int t = threadIdx.x, lane = t & 63, w = t >> 6;
    const int wm = w >> 1, wn = w & 1;
    const int l15 = lane & 15, lg = lane >> 4;
    fx4 acc[4][4] = {};
    const int skey = (t >> 3) & 7;
    const int scol0 = ((t & 7) ^ skey) * 8;
    for (int k0 = 0; k0 < 512; k0 += 64) {
        const uint16_t* ga = At + (size_t)(gm + (t >> 3)) * 512 + k0 + scol0;
        const uint16_t* gb = Pt + (size_t)(gn + (t >> 3)) * 512 + k0 + scol0;
        #pragma unroll
        for (int j = 0; j < 4; j++) {
            gload16(ga + (size_t)j * 32 * 512, &As[t * 8 + j * 2048]);
            gload16(gb + (size_t)j * 32 * 512, &Bs[t * 8 + j * 2048]);
        }
        __syncthreads();
        #pragma unroll
        for (int ks = 0; ks < 2; ks++) {
            const int kof = ks * 32 + lg * 8;
            bf16x8 af[4], bfr[4];
            #pragma unroll
            for (int m = 0; m < 4; m++) {
                const int row = wm * 64 + m * 16 + l15;
                af[m] = *reinterpret_cast<const bf16x8*>(&As[row * 64 + (kof ^ ((row & 7) << 3))]);
            }
            #pragma unroll
            for (int n = 0; n < 4; n++) {
                const int row = wn * 64 + n * 16 + l15;
                bfr[n] = *reinterpret_cast<const bf16x8*>(&Bs[row * 64 + (kof ^ ((row & 7) << 3))]);
            }
            #pragma unroll
            for (int m = 0; m < 4; m++)
                #pragma unroll
                for (int n = 0; n < 4; n++)
                    acc[m][n] = __builtin_amdgcn_mfma_f32_16x16x32_bf16(
                        af[m], bfr[n], acc[m][n], 0, 0, 0);
        }
        __syncthreads();
    }
    #pragma unroll
    for (int m = 0; m < 4; m++) {
        #pragma unroll
        for (int n = 0; n < 4; n++) {
            const int col = gn + wn * 64 + n * 16 + l15;
            const float bias = proj_b[col];
            #pragma unroll
            for (int r = 0; r < 4; r++) {
                const int row = gm + wm * 64 + m * 16 + lg * 4 + r;
                outp[(size_t)row * CDIM + col] = acc[m][n][r] + bias;
            }
        }
    }
}

// ---------------------------------------------------------------------------
// ws layout (bytes):
//   0          Wt      1572864
//   1572864    Pt       524288
//   2097152    Sq        32768   (zeroed by prep with Sk: 16384 floats)
//   2129920    Sk        32768
//   2162688    Gpart   8388608
//   10551296   attnb   1048576
//   11599872   QT     67108864   [bh][d][tok]
//   78708736   KT     67108864
//   145817600  VT     67108864   [token][c]
//   212926464  Xb/out_t 67108864 (disjoint-lifetime alias)
//   total 280035328 (~267 MB)
// ---------------------------------------------------------------------------
extern "C" void kernel_launch(void* const* d_in, const int* in_sizes, int n_in,
                              void* d_out, int out_size, void* d_ws, size_t ws_size,
                              hipStream_t stream) {
    (void)in_sizes; (void)n_in; (void)out_size; (void)ws_size;
    const float* x      = (const float*)d_in[0];
    const float* qkv_w  = (const float*)d_in[1];
    const float* q_bias = (const float*)d_in[2];
    const float* v_bias = (const float*)d_in[3];
    const float* scale  = (const float*)d_in[4];
    const float* proj_w = (const float*)d_in[5];
    const float* proj_b = (const float*)d_in[6];
    float* out = (float*)d_out;

    char* wsp = (char*)d_ws;
    uint16_t* Wt    = (uint16_t*)(wsp);
    uint16_t* Pt    = (uint16_t*)(wsp + 1572864);
    float*    Sq    = (float*)   (wsp + 2097152);
    float*    Sk    = (float*)   (wsp + 2129920);
    float*    Gpart = (float*)   (wsp + 2162688);
    uint16_t* attnb = (uint16_t*)(wsp + 10551296);
    uint16_t* QT    = (uint16_t*)(wsp + 11599872);
    uint16_t* KT    = (uint16_t*)(wsp + 78708736);
    uint16_t* VT    = (uint16_t*)(wsp + 145817600);
    uint16_t* Xb    = (uint16_t*)(wsp + 212926464);
    uint16_t* out_t = Xb;   // disjoint lifetime alias

    hipLaunchKernelGGL(transpose_w_kernel, dim3(1024), dim3(256), 0, stream,
                       qkv_w, proj_w, Wt, Pt);
    hipLaunchKernelGGL(prep_kernel, dim3(2048), dim3(256), 0, stream,
                       x, Xb, Sq);
    hipLaunchKernelGGL(gemm_qkv_kernel, dim3(6144), dim3(256), 0, stream,
                       Xb, Wt, q_bias, v_bias, QT, KT, VT, Sq, Sk);
    hipLaunchKernelGGL(attn_qk_kernel, dim3(512), dim3(256), 0, stream,
                       QT, KT, Gpart);
    hipLaunchKernelGGL(attn_finalize_kernel, dim3(128), dim3(256), 0, stream,
                       Gpart, Sq, Sk, scale, attnb);
    hipLaunchKernelGGL(pv_kernel, dim3(8192), dim3(256), 0, stream,
                       VT, attnb, out_t);
    hipLaunchKernelGGL(gemm_proj_kernel, dim3(2048), dim3(256), 0, stream,
                       out_t, Pt, proj_b, out);
}

// Round 4
// 545.544 us; speedup vs baseline: 1.7596x; 1.0605x over previous
//
#include <hip/hip_runtime.h>
#include <stdint.h>
#include <stddef.h>

#define BATCH  16
#define HEADS  8
#define NTOK   4096      // H*W
#define CDIM   512
#define FDIM   1536      // 3*C

typedef short bf16x8 __attribute__((ext_vector_type(8)));
typedef float fx4    __attribute__((ext_vector_type(4)));

__device__ __forceinline__ uint16_t f2bf(float f) {
    uint32_t u = __float_as_uint(f);
    return (uint16_t)((u + 0x7FFFu + ((u >> 16) & 1u)) >> 16); // RNE
}
__device__ __forceinline__ float bf2f(uint16_t u) {
    return __uint_as_float(((uint32_t)u) << 16);
}
// async global->LDS, 16B per lane. LDS dest must be wave-uniform base + lane*16.
__device__ __forceinline__ void gload16(const uint16_t* g, uint16_t* l) {
    __builtin_amdgcn_global_load_lds(
        (const __attribute__((address_space(1))) uint32_t*)(g),
        (__attribute__((address_space(3))) uint32_t*)(l), 16, 0, 0);
}
// XOR-swizzled index into a [R][128] u16 LDS tile
__device__ __forceinline__ int cidx(int row, int col) {
    return row * 128 + (col ^ ((row & 7) << 3));
}

// ---------------------------------------------------------------------------
// transpose_w: Wt[f][c] = bf16(qkv_w[c][f]); Pt[f][c] = bf16(proj_w[c][f])
// ---------------------------------------------------------------------------
__global__ void transpose_w_kernel(const float* __restrict__ qkv_w,
                                   const float* __restrict__ proj_w,
                                   uint16_t* __restrict__ Wt,
                                   uint16_t* __restrict__ Pt) {
    __shared__ uint16_t tile[32][33];
    int blk = blockIdx.x;
    const float* src; uint16_t* dst; int W, Hh, r0, c0;
    if (blk < 768) {                    // qkv_w: 512 x 1536
        int tr = blk / 48, tc = blk % 48;
        src = qkv_w; dst = Wt; W = 1536; Hh = 512; r0 = tr * 32; c0 = tc * 32;
    } else {                            // proj_w: 512 x 512
        blk -= 768;
        int tr = blk / 16, tc = blk % 16;
        src = proj_w; dst = Pt; W = 512; Hh = 512; r0 = tr * 32; c0 = tc * 32;
    }
    const int tx = threadIdx.x & 31, ty = threadIdx.x >> 5;   // 32 x 8
    #pragma unroll
    for (int j = 0; j < 4; j++)
        tile[ty + 8 * j][tx] = f2bf(src[(size_t)(r0 + ty + 8 * j) * W + c0 + tx]);
    __syncthreads();
    #pragma unroll
    for (int j = 0; j < 4; j++)
        dst[(size_t)(c0 + ty + 8 * j) * Hh + r0 + tx] = tile[tx][ty + 8 * j];
}

// ---------------------------------------------------------------------------
// prep: Xb = bf16(x); zero Sq/Sk (16384 contiguous floats at Sq)
// ---------------------------------------------------------------------------
__global__ void prep_kernel(const float* __restrict__ X,
                            uint16_t* __restrict__ Xb,
                            float* __restrict__ Sqk) {
    const int tid = blockIdx.x * blockDim.x + threadIdx.x;
    const int stride = gridDim.x * blockDim.x;
    for (int i = tid; i < (1 << 22); i += stride) {
        const fx4* src = reinterpret_cast<const fx4*>(X + (size_t)i * 8);
        fx4 v0 = src[0], v1 = src[1];
        union { bf16x8 v; uint16_t u[8]; } pk;
        #pragma unroll
        for (int e = 0; e < 4; e++) { pk.u[e] = f2bf(v0[e]); pk.u[4 + e] = f2bf(v1[e]); }
        reinterpret_cast<bf16x8*>(Xb)[i] = pk.v;
    }
    for (int i = tid; i < 16384; i += stride) Sqk[i] = 0.0f;
}

// ---------------------------------------------------------------------------
// qkv GEMM, ring-pipelined (counted vmcnt, never 0 in main loop):
// 128x128 tile, BK=32, 16 K-tiles, 4-slot LDS ring (64 KB), 3-deep prefetch.
// Per iter: waitcnt(vm 8, lgkm 0); s_barrier; stage kt+3; 8 ds_read; 16 MFMA.
// Epilogue: layout-split via swizzled LDS C-tile + fused sumsq (unchanged).
// ---------------------------------------------------------------------------
__global__ __launch_bounds__(256) void gemm_qkv_kernel(
        const uint16_t* __restrict__ Xb, const uint16_t* __restrict__ Wt,
        const float* __restrict__ q_bias, const float* __restrict__ v_bias,
        uint16_t* __restrict__ QT, uint16_t* __restrict__ KT,
        uint16_t* __restrict__ VT,
        float* __restrict__ Sq, float* __restrict__ Sk) {
    __shared__ uint16_t ring[4][8192];   // slot: [0..4095]=A(128x32), [4096..8191]=B
    const int bx = blockIdx.x;
    const int swz = (bx & 7) * 768 + (bx >> 3); // nwg=6144, bijective XCD swizzle
    const int tm = swz / 12, tn = swz % 12;
    const int gm = tm * 128, gn = tn * 128;
    const int b = gm >> 12, tok0 = gm & 4095;
    const int t = threadIdx.x, lane = t & 63, w = t >> 6;
    const int wm = w >> 1, wn = w & 1;
    const int l15 = lane & 15, lg = lane >> 4;
    fx4 acc[4][4] = {};
    // staging geometry: thread t loads rows {srow, 64+srow} at swizzled col scol
    const int srow = t >> 2;
    const int scol = (((t & 3) ^ (srow & 3)) << 3);
    const uint16_t* gA = Xb + (size_t)(gm + srow) * 512 + scol;
    const uint16_t* gB = Wt + (size_t)(gn + srow) * 512 + scol;
#define STAGE_QKV(kt_) do {                                                   \
        const int s_ = (kt_) & 3; const int k0_ = (kt_) * 32;                 \
        gload16(gA + k0_,                 &ring[s_][t * 8]);                  \
        gload16(gA + (size_t)64*512 + k0_, &ring[s_][t * 8 + 2048]);          \
        gload16(gB + k0_,                 &ring[s_][4096 + t * 8]);           \
        gload16(gB + (size_t)64*512 + k0_, &ring[s_][4096 + t * 8 + 2048]);   \
    } while (0)
    STAGE_QKV(0); STAGE_QKV(1); STAGE_QKV(2);
    #pragma unroll
    for (int kt = 0; kt < 16; ++kt) {
        if (kt < 14)       asm volatile("s_waitcnt vmcnt(8) lgkmcnt(0)" ::: "memory");
        else if (kt == 14) asm volatile("s_waitcnt vmcnt(4) lgkmcnt(0)" ::: "memory");
        else               asm volatile("s_waitcnt vmcnt(0) lgkmcnt(0)" ::: "memory");
        __builtin_amdgcn_s_barrier();
        if (kt < 13) STAGE_QKV(kt + 3);
        const uint16_t* As = &ring[kt & 3][0];
        const uint16_t* Bs = &ring[kt & 3][4096];
        bf16x8 af[4], bfr[4];
        #pragma unroll
        for (int m = 0; m < 4; m++) {
            const int row = wm * 64 + m * 16 + l15;
            af[m] = *reinterpret_cast<const bf16x8*>(&As[row * 32 + ((lg ^ (row & 3)) << 3)]);
        }
        #pragma unroll
        for (int n = 0; n < 4; n++) {
            const int row = wn * 64 + n * 16 + l15;
            bfr[n] = *reinterpret_cast<const bf16x8*>(&Bs[row * 32 + ((lg ^ (row & 3)) << 3)]);
        }
        __builtin_amdgcn_s_setprio(1);
        #pragma unroll
        for (int m = 0; m < 4; m++)
            #pragma unroll
            for (int n = 0; n < 4; n++)
                acc[m][n] = __builtin_amdgcn_mfma_f32_16x16x32_bf16(
                    af[m], bfr[n], acc[m][n], 0, 0, 0);
        __builtin_amdgcn_s_setprio(0);
    }
#undef STAGE_QKV
    __syncthreads();
    // ---- stage C tile (bias fused) into swizzled LDS (reuse ring) ----
    uint16_t* sh = &ring[0][0];   // 32 KB C-tile
    #pragma unroll
    for (int n = 0; n < 4; n++) {
        const int col = gn + wn * 64 + n * 16 + l15;
        const float bias = (col < 512) ? q_bias[col]
                          : ((col < 1024) ? 0.0f : v_bias[col - 1024]);
        #pragma unroll
        for (int m = 0; m < 4; m++)
            #pragma unroll
            for (int r = 0; r < 4; r++) {
                const int lrow = wm * 64 + m * 16 + lg * 4 + r;
                const int lcol = wn * 64 + n * 16 + l15;
                sh[cidx(lrow, lcol)] = f2bf(acc[m][n][r] + bias);
            }
    }
    __syncthreads();
    // ---- layout-split write: 2 chunks of 64 cols ----
    const int cc = t >> 7, tloc = t & 127;
    const int u = (gn >> 6) + cc;
    const int h = u / 3, which = u % 3;
    const int bh = b * 8 + h;
    if (which < 2) {   // q or k -> [bh][d][tok] + sumsq
        const int d = tloc & 63, oct = tloc >> 6;
        uint16_t* dst = (which == 0 ? QT : KT)
                        + ((size_t)bh * 64 + d) * 4096 + tok0 + oct * 64;
        float ss = 0.f;
        #pragma unroll
        for (int g = 0; g < 8; g++) {
            union { bf16x8 v; uint16_t u16v[8]; } pk;
            #pragma unroll
            for (int s2 = 0; s2 < 8; s2++) {
                uint16_t val = sh[cidx(oct * 64 + g * 8 + s2, cc * 64 + d)];
                pk.u16v[s2] = val;
                float f = bf2f(val);
                ss += f * f;
            }
            *reinterpret_cast<bf16x8*>(dst + g * 8) = pk.v;
        }
        atomicAdd((which == 0 ? Sq : Sk) + bh * 64 + d, ss);
    } else {           // v -> VT[token][h*64+e]
        const int tok = tloc;
        uint16_t* dst = VT + (size_t)(gm + tok) * 512 + h * 64;
        #pragma unroll
        for (int bb = 0; bb < 8; bb++) {
            bf16x8 v = *reinterpret_cast<const bf16x8*>(&sh[cidx(tok, cc * 64 + bb * 8)]);
            *reinterpret_cast<bf16x8*>(dst + bb * 8) = v;
        }
    }
}

// ---------------------------------------------------------------------------
// attn_qk: Gpart[quarter][bh][d][e] = sum_{n in quarter} q[d,n]*k[e,n]
// ---------------------------------------------------------------------------
__global__ __launch_bounds__(256) void attn_qk_kernel(
        const uint16_t* __restrict__ QT, const uint16_t* __restrict__ KT,
        float* __restrict__ Gpart) {
    __shared__ uint16_t Qs[64 * 128];
    __shared__ uint16_t Ks[64 * 128];
    const int blk = blockIdx.x;
    const int bh = blk >> 2, quarter = blk & 3;
    const int t = threadIdx.x, lane = t & 63, w = t >> 6;
    const int l15 = lane & 15, lg = lane >> 4;
    const int wr = w >> 1, wc = w & 1;
    fx4 acc[2][2] = {};
    const uint16_t* qbase = QT + (size_t)bh * 64 * 4096;
    const uint16_t* kbase = KT + (size_t)bh * 64 * 4096;
    for (int it = 0; it < 8; it++) {
        const int tokt = quarter * 1024 + it * 128;
        #pragma unroll
        for (int j = 0; j < 4; j++) {
            const int li = j * 256 + t;
            const int row = li >> 4;
            const int src_off = (((li & 15) ^ (row & 7)) << 3);
            gload16(qbase + (size_t)row * 4096 + tokt + src_off, &Qs[li * 8]);
            gload16(kbase + (size_t)row * 4096 + tokt + src_off, &Ks[li * 8]);
        }
        __syncthreads();
        #pragma unroll
        for (int ks = 0; ks < 4; ks++) {
            const int kof = ks * 32 + lg * 8;
            const int ra0 = wr * 32 + l15,      ra1 = wr * 32 + 16 + l15;
            const int rb0 = wc * 32 + l15,      rb1 = wc * 32 + 16 + l15;
            bf16x8 a0 = *reinterpret_cast<const bf16x8*>(&Qs[ra0 * 128 + (kof ^ ((ra0 & 7) << 3))]);
            bf16x8 a1 = *reinterpret_cast<const bf16x8*>(&Qs[ra1 * 128 + (kof ^ ((ra1 & 7) << 3))]);
            bf16x8 b0 = *reinterpret_cast<const bf16x8*>(&Ks[rb0 * 128 + (kof ^ ((rb0 & 7) << 3))]);
            bf16x8 b1 = *reinterpret_cast<const bf16x8*>(&Ks[rb1 * 128 + (kof ^ ((rb1 & 7) << 3))]);
            acc[0][0] = __builtin_amdgcn_mfma_f32_16x16x32_bf16(a0, b0, acc[0][0], 0, 0, 0);
            acc[0][1] = __builtin_amdgcn_mfma_f32_16x16x32_bf16(a0, b1, acc[0][1], 0, 0, 0);
            acc[1][0] = __builtin_amdgcn_mfma_f32_16x16x32_bf16(a1, b0, acc[1][0], 0, 0, 0);
            acc[1][1] = __builtin_amdgcn_mfma_f32_16x16x32_bf16(a1, b1, acc[1][1], 0, 0, 0);
        }
        __syncthreads();
    }
    float* gp = Gpart + (size_t)quarter * 524288 + (size_t)bh * 4096;
    #pragma unroll
    for (int mi = 0; mi < 2; mi++)
        #pragma unroll
        for (int ni = 0; ni < 2; ni++)
            #pragma unroll
            for (int r = 0; r < 4; r++) {
                const int d = wr * 32 + mi * 16 + lg * 4 + r;
                const int e = wc * 32 + ni * 16 + l15;
                gp[d * 64 + e] = acc[mi][ni][r];
            }
}

// ---------------------------------------------------------------------------
// finalize: attnb[bh][d][e] = bf16( softmax_e( exp(scale_h)*G*rq[d]*rk[e] ) )
// ---------------------------------------------------------------------------
__global__ void attn_finalize_kernel(const float* __restrict__ Gpart,
                                     const float* __restrict__ Sq,
                                     const float* __restrict__ Sk,
                                     const float* __restrict__ scale,
                                     uint16_t* __restrict__ attnb) {
    const int bh = blockIdx.x;
    const int h = bh & 7;
    const int t = threadIdx.x;           // 256
    const int e = t & 63, w = t >> 6;
    const float es = expf(scale[h]);
    const float rk = rsqrtf(fmaxf(Sk[bh * 64 + e], 1.55e-5f));
    const float* g0 = Gpart + (size_t)bh * 4096;
    for (int d = w; d < 64; d += 4) {
        const float rq = rsqrtf(fmaxf(Sq[bh * 64 + d], 1.55e-5f));
        float g = g0[d * 64 + e] + g0[524288 + d * 64 + e]
                + g0[1048576 + d * 64 + e] + g0[1572864 + d * 64 + e];
        float x = es * g * rq * rk;
        float m = x;
        #pragma unroll
        for (int off = 32; off; off >>= 1) m = fmaxf(m, __shfl_xor(m, off, 64));
        float p = expf(x - m);
        float s = p;
        #pragma unroll
        for (int off = 32; off; off >>= 1) s += __shfl_xor(s, off, 64);
        attnb[(size_t)bh * 4096 + d * 64 + e] = f2bf(p / s);
    }
}

// ---------------------------------------------------------------------------
// pv (MFMA): out_t[n][h*64+d] = sum_e attnb[bh][d][e] * v[n][e]
// C staged through LDS -> packed b128 global stores (full 64B sectors).
// ---------------------------------------------------------------------------
__global__ __launch_bounds__(256) void pv_kernel(
        const uint16_t* __restrict__ VT, const uint16_t* __restrict__ attnb,
        uint16_t* __restrict__ out_t) {
    __shared__ uint16_t Vs[64 * 64];   // 8 KB
    __shared__ uint16_t Os[64 * 64];   // 8 KB
    const int blk = blockIdx.x;
    const int bh = blk >> 6, chunk = blk & 63;
    const int b = bh >> 3, h = bh & 7;
    const int n0 = chunk * 64;
    const int t = threadIdx.x, lane = t & 63, w = t >> 6;
    const int l15 = lane & 15, lg = lane >> 4;
    #pragma unroll
    for (int j = 0; j < 2; j++) {
        const int li = j * 256 + t;
        const int row = li >> 3;
        const int src_off = (((li & 7) ^ (row & 7)) << 3);
        gload16(VT + (size_t)(b * NTOK + n0 + row) * 512 + h * 64 + src_off, &Vs[li * 8]);
    }
    bf16x8 bfr[4][2];
    const uint16_t* ab = attnb + (size_t)bh * 4096;
    #pragma unroll
    for (int n = 0; n < 4; n++)
        #pragma unroll
        for (int ks = 0; ks < 2; ks++)
            bfr[n][ks] = *reinterpret_cast<const bf16x8*>(ab + (n * 16 + l15) * 64 + ks * 32 + lg * 8);
    __syncthreads();
    fx4 acc[4] = {};
    #pragma unroll
    for (int ks = 0; ks < 2; ks++) {
        const int row = w * 16 + l15;
        const int kof = ks * 32 + lg * 8;
        bf16x8 a = *reinterpret_cast<const bf16x8*>(&Vs[row * 64 + (kof ^ ((row & 7) << 3))]);
        #pragma unroll
        for (int n = 0; n < 4; n++)
            acc[n] = __builtin_amdgcn_mfma_f32_16x16x32_bf16(a, bfr[n][ks], acc[n], 0, 0, 0);
    }
    #pragma unroll
    for (int n = 0; n < 4; n++)
        #pragma unroll
        for (int r = 0; r < 4; r++) {
            const int row = w * 16 + lg * 4 + r;
            const int col = n * 16 + l15;
            Os[row * 64 + (col ^ ((row & 7) << 3))] = f2bf(acc[n][r]);
        }
    __syncthreads();
    {
        const int tr = t >> 2, c0 = (t & 3) * 16;
        uint16_t* orow = out_t + (size_t)(b * NTOK + n0 + tr) * CDIM + h * 64;
        #pragma unroll
        for (int cc2 = 0; cc2 < 2; cc2++) {
            const int c = c0 + cc2 * 8;
            const int chnk = (c >> 3) ^ (tr & 7);
            bf16x8 vv = *reinterpret_cast<const bf16x8*>(&Os[tr * 64 + (chnk << 3)]);
            *reinterpret_cast<bf16x8*>(orow + c) = vv;
        }
    }
}

// ---------------------------------------------------------------------------
// proj GEMM, same ring pipeline: out[M][512] = out_t @ Pt^T + proj_b (fp32)
// ---------------------------------------------------------------------------
__global__ __launch_bounds__(256) void gemm_proj_kernel(
        const uint16_t* __restrict__ At, const uint16_t* __restrict__ Pt,
        const float* __restrict__ proj_b, float* __restrict__ outp) {
    __shared__ uint16_t ring[4][8192];
    const int bx = blockIdx.x;
    const int swz = (bx & 7) * 256 + (bx >> 3);   // nwg=2048, bijective
    const int tn = swz & 3, tm = swz >> 2;
    const int gm = tm * 128, gn = tn * 128;
    const int t = threadIdx.x, lane = t & 63, w = t >> 6;
    const int wm = w >> 1, wn = w & 1;
    const int l15 = lane & 15, lg = lane >> 4;
    fx4 acc[4][4] = {};
    const int srow = t >> 2;
    const int scol = (((t & 3) ^ (srow & 3)) << 3);
    const uint16_t* gA = At + (size_t)(gm + srow) * 512 + scol;
    const uint16_t* gB = Pt + (size_t)(gn + srow) * 512 + scol;
#define STAGE_PROJ(kt_) do {                                                  \
        const int s_ = (kt_) & 3; const int k0_ = (kt_) * 32;                 \
        gload16(gA + k0_,                 &ring[s_][t * 8]);                  \
        gload16(gA + (size_t)64*512 + k0_, &ring[s_][t * 8 + 2048]);          \
        gload16(gB + k0_,                 &ring[s_][4096 + t * 8]);           \
        gload16(gB + (size_t)64*512 + k0_, &ring[s_][4096 + t * 8 + 2048]);   \
    } while (0)
    STAGE_PROJ(0); STAGE_PROJ(1); STAGE_PROJ(2);
    #pragma unroll
    for (int kt = 0; kt < 16; ++kt) {
        if (kt < 14)       asm volatile("s_waitcnt vmcnt(8) lgkmcnt(0)" ::: "memory");
        else if (kt == 14) asm volatile("s_waitcnt vmcnt(4) lgkmcnt(0)" ::: "memory");
        else               asm volatile("s_waitcnt vmcnt(0) lgkmcnt(0)" ::: "memory");
        __builtin_amdgcn_s_barrier();
        if (kt < 13) STAGE_PROJ(kt + 3);
        const uint16_t* As = &ring[kt & 3][0];
        const uint16_t* Bs = &ring[kt & 3][4096];
        bf16x8 af[4], bfr[4];
        #pragma unroll
        for (int m = 0; m < 4; m++) {
            const int row = wm * 64 + m * 16 + l15;
            af[m] = *reinterpret_cast<const bf16x8*>(&As[row * 32 + ((lg ^ (row & 3)) << 3)]);
        }
        #pragma unroll
        for (int n = 0; n < 4; n++) {
            const int row = wn * 64 + n * 16 + l15;
            bfr[n] = *reinterpret_cast<const bf16x8*>(&Bs[row * 32 + ((lg ^ (row & 3)) << 3)]);
        }
        __builtin_amdgcn_s_setprio(1);
        #pragma unroll
        for (int m = 0; m < 4; m++)
            #pragma unroll
            for (int n = 0; n < 4; n++)
                acc[m][n] = __builtin_amdgcn_mfma_f32_16x16x32_bf16(
                    af[m], bfr[n], acc[m][n], 0, 0, 0);
        __builtin_amdgcn_s_setprio(0);
    }
#undef STAGE_PROJ
    #pragma unroll
    for (int m = 0; m < 4; m++) {
        #pragma unroll
        for (int n = 0; n < 4; n++) {
            const int col = gn + wn * 64 + n * 16 + l15;
            const float bias = proj_b[col];
            #pragma unroll
            for (int r = 0; r < 4; r++) {
                const int row = gm + wm * 64 + m * 16 + lg * 4 + r;
                outp[(size_t)row * CDIM + col] = acc[m][n][r] + bias;
            }
        }
    }
}

// ---------------------------------------------------------------------------
// ws layout (bytes):
//   0          Wt      1572864
//   1572864    Pt       524288
//   2097152    Sq        32768
//   2129920    Sk        32768
//   2162688    Gpart   8388608
//   10551296   attnb   1048576
//   11599872   QT     67108864   [bh][d][tok]
//   78708736   KT     67108864
//   145817600  VT     67108864   [token][c]
//   212926464  Xb/out_t 67108864 (disjoint-lifetime alias)
//   total 280035328 (~267 MB)
// ---------------------------------------------------------------------------
extern "C" void kernel_launch(void* const* d_in, const int* in_sizes, int n_in,
                              void* d_out, int out_size, void* d_ws, size_t ws_size,
                              hipStream_t stream) {
    (void)in_sizes; (void)n_in; (void)out_size; (void)ws_size;
    const float* x      = (const float*)d_in[0];
    const float* qkv_w  = (const float*)d_in[1];
    const float* q_bias = (const float*)d_in[2];
    const float* v_bias = (const float*)d_in[3];
    const float* scale  = (const float*)d_in[4];
    const float* proj_w = (const float*)d_in[5];
    const float* proj_b = (const float*)d_in[6];
    float* out = (float*)d_out;

    char* wsp = (char*)d_ws;
    uint16_t* Wt    = (uint16_t*)(wsp);
    uint16_t* Pt    = (uint16_t*)(wsp + 1572864);
    float*    Sq    = (float*)   (wsp + 2097152);
    float*    Sk    = (float*)   (wsp + 2129920);
    float*    Gpart = (float*)   (wsp + 2162688);
    uint16_t* attnb = (uint16_t*)(wsp + 10551296);
    uint16_t* QT    = (uint16_t*)(wsp + 11599872);
    uint16_t* KT    = (uint16_t*)(wsp + 78708736);
    uint16_t* VT    = (uint16_t*)(wsp + 145817600);
    uint16_t* Xb    = (uint16_t*)(wsp + 212926464);
    uint16_t* out_t = Xb;   // disjoint lifetime alias

    hipLaunchKernelGGL(transpose_w_kernel, dim3(1024), dim3(256), 0, stream,
                       qkv_w, proj_w, Wt, Pt);
    hipLaunchKernelGGL(prep_kernel, dim3(2048), dim3(256), 0, stream,
                       x, Xb, Sq);
    hipLaunchKernelGGL(gemm_qkv_kernel, dim3(6144), dim3(256), 0, stream,
                       Xb, Wt, q_bias, v_bias, QT, KT, VT, Sq, Sk);
    hipLaunchKernelGGL(attn_qk_kernel, dim3(512), dim3(256), 0, stream,
                       QT, KT, Gpart);
    hipLaunchKernelGGL(attn_finalize_kernel, dim3(128), dim3(256), 0, stream,
                       Gpart, Sq, Sk, scale, attnb);
    hipLaunchKernelGGL(pv_kernel, dim3(8192), dim3(256), 0, stream,
                       VT, attnb, out_t);
    hipLaunchKernelGGL(gemm_proj_kernel, dim3(2048), dim3(256), 0, stream,
                       out_t, Pt, proj_b, out);
}

// Round 5
// 531.157 us; speedup vs baseline: 1.8072x; 1.0271x over previous
//
#include <hip/hip_runtime.h>
#include <stdint.h>
#include <stddef.h>

#define BATCH  16
#define HEADS  8
#define NTOK   4096      // H*W
#define CDIM   512
#define FDIM   1536      // 3*C

typedef short bf16x8 __attribute__((ext_vector_type(8)));
typedef float fx4    __attribute__((ext_vector_type(4)));

__device__ __forceinline__ uint16_t f2bf(float f) {
    uint32_t u = __float_as_uint(f);
    return (uint16_t)((u + 0x7FFFu + ((u >> 16) & 1u)) >> 16); // RNE
}
__device__ __forceinline__ float bf2f(uint16_t u) {
    return __uint_as_float(((uint32_t)u) << 16);
}
// async global->LDS, 16B per lane. LDS dest must be wave-uniform base + lane*16.
__device__ __forceinline__ void gload16(const uint16_t* g, uint16_t* l) {
    __builtin_amdgcn_global_load_lds(
        (const __attribute__((address_space(1))) uint32_t*)(g),
        (__attribute__((address_space(3))) uint32_t*)(l), 16, 0, 0);
}

// ---------------------------------------------------------------------------
// transpose_w: Wt[f][c] = bf16(qkv_w[c][f]); Pt[f][c] = bf16(proj_w[c][f])
// ---------------------------------------------------------------------------
__global__ void transpose_w_kernel(const float* __restrict__ qkv_w,
                                   const float* __restrict__ proj_w,
                                   uint16_t* __restrict__ Wt,
                                   uint16_t* __restrict__ Pt) {
    __shared__ uint16_t tile[32][33];
    int blk = blockIdx.x;
    const float* src; uint16_t* dst; int W, Hh, r0, c0;
    if (blk < 768) {                    // qkv_w: 512 x 1536
        int tr = blk / 48, tc = blk % 48;
        src = qkv_w; dst = Wt; W = 1536; Hh = 512; r0 = tr * 32; c0 = tc * 32;
    } else {                            // proj_w: 512 x 512
        blk -= 768;
        int tr = blk / 16, tc = blk % 16;
        src = proj_w; dst = Pt; W = 512; Hh = 512; r0 = tr * 32; c0 = tc * 32;
    }
    const int tx = threadIdx.x & 31, ty = threadIdx.x >> 5;   // 32 x 8
    #pragma unroll
    for (int j = 0; j < 4; j++)
        tile[ty + 8 * j][tx] = f2bf(src[(size_t)(r0 + ty + 8 * j) * W + c0 + tx]);
    __syncthreads();
    #pragma unroll
    for (int j = 0; j < 4; j++)
        dst[(size_t)(c0 + ty + 8 * j) * Hh + r0 + tx] = tile[tx][ty + 8 * j];
}

// ---------------------------------------------------------------------------
// prep: Xb = bf16(x); zero Sq/Sk (16384 contiguous floats at Sq)
// ---------------------------------------------------------------------------
__global__ void prep_kernel(const float* __restrict__ X,
                            uint16_t* __restrict__ Xb,
                            float* __restrict__ Sqk) {
    const int tid = blockIdx.x * blockDim.x + threadIdx.x;
    const int stride = gridDim.x * blockDim.x;
    for (int i = tid; i < (1 << 22); i += stride) {
        const fx4* src = reinterpret_cast<const fx4*>(X + (size_t)i * 8);
        fx4 v0 = src[0], v1 = src[1];
        union { bf16x8 v; uint16_t u[8]; } pk;
        #pragma unroll
        for (int e = 0; e < 4; e++) { pk.u[e] = f2bf(v0[e]); pk.u[4 + e] = f2bf(v1[e]); }
        reinterpret_cast<bf16x8*>(Xb)[i] = pk.v;
    }
    for (int i = tid; i < 16384; i += stride) Sqk[i] = 0.0f;
}

// ---------------------------------------------------------------------------
// qkv GEMM, 3-slot ring (48 KB -> 3 blocks/CU), counted vmcnt.
// Epilogue: q/k stored DIRECT from acc (C-layout row runs) + shfl sumsq;
// v re-staged through 16 KB swizzled LDS for coalesced VT rows.
// ---------------------------------------------------------------------------
__global__ __launch_bounds__(256) void gemm_qkv_kernel(
        const uint16_t* __restrict__ Xb, const uint16_t* __restrict__ Wt,
        const float* __restrict__ q_bias, const float* __restrict__ v_bias,
        uint16_t* __restrict__ QT, uint16_t* __restrict__ KT,
        uint16_t* __restrict__ VT,
        float* __restrict__ Sq, float* __restrict__ Sk) {
    __shared__ uint16_t ring[3][8192];   // slot: [0..4095]=A(128x32), [4096..8191]=B
    const int bx = blockIdx.x;
    const int swz = (bx & 7) * 768 + (bx >> 3); // nwg=6144, bijective XCD swizzle
    const int tm = swz / 12, tn = swz % 12;
    const int gm = tm * 128, gn = tn * 128;
    const int b = gm >> 12, tok0 = gm & 4095;
    const int t = threadIdx.x, lane = t & 63, w = t >> 6;
    const int wm = w >> 1, wn = w & 1;
    const int l15 = lane & 15, lg = lane >> 4;
    fx4 acc[4][4] = {};
    const int srow = t >> 2;
    const int scol = (((t & 3) ^ (srow & 3)) << 3);
    const uint16_t* gA = Xb + (size_t)(gm + srow) * 512 + scol;
    const uint16_t* gB = Wt + (size_t)(gn + srow) * 512 + scol;
    auto stage = [&](int kt_) {
        const int s_ = kt_ % 3;
        const int k0_ = kt_ * 32;
        gload16(gA + k0_,                    &ring[s_][t * 8]);
        gload16(gA + (size_t)64 * 512 + k0_, &ring[s_][t * 8 + 2048]);
        gload16(gB + k0_,                    &ring[s_][4096 + t * 8]);
        gload16(gB + (size_t)64 * 512 + k0_, &ring[s_][4096 + t * 8 + 2048]);
    };
    stage(0); stage(1);
    #pragma unroll
    for (int kt = 0; kt < 16; ++kt) {
        if (kt < 15) asm volatile("s_waitcnt vmcnt(4) lgkmcnt(0)" ::: "memory");
        else         asm volatile("s_waitcnt vmcnt(0) lgkmcnt(0)" ::: "memory");
        __builtin_amdgcn_s_barrier();
        if (kt < 14) stage(kt + 2);
        const uint16_t* As = &ring[kt % 3][0];
        const uint16_t* Bs = &ring[kt % 3][4096];
        bf16x8 af[4], bfr[4];
        #pragma unroll
        for (int m = 0; m < 4; m++) {
            const int row = wm * 64 + m * 16 + l15;
            af[m] = *reinterpret_cast<const bf16x8*>(&As[row * 32 + ((lg ^ (row & 3)) << 3)]);
        }
        #pragma unroll
        for (int n = 0; n < 4; n++) {
            const int row = wn * 64 + n * 16 + l15;
            bfr[n] = *reinterpret_cast<const bf16x8*>(&Bs[row * 32 + ((lg ^ (row & 3)) << 3)]);
        }
        __builtin_amdgcn_s_setprio(1);
        #pragma unroll
        for (int m = 0; m < 4; m++)
            #pragma unroll
            for (int n = 0; n < 4; n++)
                acc[m][n] = __builtin_amdgcn_mfma_f32_16x16x32_bf16(
                    af[m], bfr[n], acc[m][n], 0, 0, 0);
        __builtin_amdgcn_s_setprio(0);
    }
    __syncthreads();
    // ---- epilogue: chunk identity for this thread's wn half ----
    const int u = (gn >> 6) + wn;
    const int type = u % 3;               // 0=q 1=k 2=v
    const int h = u / 3;
    const int bh = b * 8 + h;
    float biasn[4];
    #pragma unroll
    for (int n = 0; n < 4; n++) {
        const int col = gn + wn * 64 + n * 16 + l15;   // flat f column
        biasn[n] = (col < 512) ? q_bias[col]
                  : ((col < 1024) ? 0.0f : v_bias[col - 1024]);
    }
    if (type < 2) {   // q/k: direct transposed store + fused sumsq
        uint16_t* T = (type == 0) ? QT : KT;
        #pragma unroll
        for (int n = 0; n < 4; n++) {
            const int d = n * 16 + l15;
            uint16_t* dst = T + ((size_t)bh * 64 + d) * 4096 + tok0 + wm * 64 + lg * 4;
            float ss = 0.f;
            #pragma unroll
            for (int m = 0; m < 4; m++) {
                union { uint16_t u4[4]; uint64_t q; } pk;
                #pragma unroll
                for (int r = 0; r < 4; r++) {
                    const float f = acc[m][n][r] + biasn[n];
                    pk.u4[r] = f2bf(f);
                    ss += f * f;
                }
                *reinterpret_cast<uint64_t*>(dst + m * 16) = pk.q;
            }
            ss += __shfl_xor(ss, 16, 64);
            ss += __shfl_xor(ss, 32, 64);
            if (lg == 0)
                atomicAdd((type == 0 ? Sq : Sk) + bh * 64 + d, ss);
        }
    } else {          // v: stage into swizzled LDS [128][64] (ring slot 0)
        uint16_t* vs = &ring[0][0];
        #pragma unroll
        for (int n = 0; n < 4; n++) {
            const int lcol = n * 16 + l15;
            #pragma unroll
            for (int m = 0; m < 4; m++)
                #pragma unroll
                for (int r = 0; r < 4; r++) {
                    const int lrow = wm * 64 + m * 16 + lg * 4 + r;
                    vs[lrow * 64 + (lcol ^ ((lrow & 7) << 3))] =
                        f2bf(acc[m][n][r] + biasn[n]);
                }
        }
    }
    __syncthreads();
    // ---- cooperative v write-out (if this block contains a v chunk) ----
    {
        const int u0 = gn >> 6;
        const int uv = (u0 % 3 == 2) ? u0 : (((u0 + 1) % 3 == 2) ? (u0 + 1) : -1);
        if (uv >= 0) {
            const uint16_t* vs = &ring[0][0];
            const int hv = uv / 3;
            const int row = t >> 1, c0v = (t & 1) * 32;
            uint16_t* dst = VT + (size_t)(gm + row) * 512 + hv * 64 + c0v;
            #pragma unroll
            for (int cc = 0; cc < 4; cc++) {
                const int col = c0v + cc * 8;
                bf16x8 vv = *reinterpret_cast<const bf16x8*>(
                    &vs[row * 64 + (col ^ ((row & 7) << 3))]);
                *reinterpret_cast<bf16x8*>(dst + cc * 8) = vv;
            }
        }
    }
}

// ---------------------------------------------------------------------------
// attn_qk: Gpart[quarter][bh][d][e] = sum_{n in quarter} q[d,n]*k[e,n]
// double-buffered: stage tile it+1 after barrier, overlapping compute(it).
// ---------------------------------------------------------------------------
__global__ __launch_bounds__(256) void attn_qk_kernel(
        const uint16_t* __restrict__ QT, const uint16_t* __restrict__ KT,
        float* __restrict__ Gpart) {
    __shared__ uint16_t Qs[2][8192];
    __shared__ uint16_t Ks[2][8192];
    const int blk = blockIdx.x;
    const int bh = blk >> 2, quarter = blk & 3;
    const int t = threadIdx.x, lane = t & 63, w = t >> 6;
    const int l15 = lane & 15, lg = lane >> 4;
    const int wr = w >> 1, wc = w & 1;
    fx4 acc[2][2] = {};
    const uint16_t* qbase = QT + (size_t)bh * 64 * 4096;
    const uint16_t* kbase = KT + (size_t)bh * 64 * 4096;
    auto stage = [&](int it_) {
        const int tokt = quarter * 1024 + it_ * 128;
        uint16_t* qd = &Qs[it_ & 1][0];
        uint16_t* kd = &Ks[it_ & 1][0];
        #pragma unroll
        for (int j = 0; j < 4; j++) {
            const int li = j * 256 + t;
            const int row = li >> 4;
            const int src_off = (((li & 15) ^ (row & 7)) << 3);
            gload16(qbase + (size_t)row * 4096 + tokt + src_off, qd + li * 8);
            gload16(kbase + (size_t)row * 4096 + tokt + src_off, kd + li * 8);
        }
    };
    stage(0);
    for (int it = 0; it < 8; it++) {
        asm volatile("s_waitcnt vmcnt(0) lgkmcnt(0)" ::: "memory");
        __builtin_amdgcn_s_barrier();
        if (it < 7) stage(it + 1);
        const uint16_t* Qb = &Qs[it & 1][0];
        const uint16_t* Kb = &Ks[it & 1][0];
        #pragma unroll
        for (int ks = 0; ks < 4; ks++) {
            const int kof = ks * 32 + lg * 8;
            const int ra0 = wr * 32 + l15,      ra1 = wr * 32 + 16 + l15;
            const int rb0 = wc * 32 + l15,      rb1 = wc * 32 + 16 + l15;
            bf16x8 a0 = *reinterpret_cast<const bf16x8*>(&Qb[ra0 * 128 + (kof ^ ((ra0 & 7) << 3))]);
            bf16x8 a1 = *reinterpret_cast<const bf16x8*>(&Qb[ra1 * 128 + (kof ^ ((ra1 & 7) << 3))]);
            bf16x8 b0 = *reinterpret_cast<const bf16x8*>(&Kb[rb0 * 128 + (kof ^ ((rb0 & 7) << 3))]);
            bf16x8 b1 = *reinterpret_cast<const bf16x8*>(&Kb[rb1 * 128 + (kof ^ ((rb1 & 7) << 3))]);
            acc[0][0] = __builtin_amdgcn_mfma_f32_16x16x32_bf16(a0, b0, acc[0][0], 0, 0, 0);
            acc[0][1] = __builtin_amdgcn_mfma_f32_16x16x32_bf16(a0, b1, acc[0][1], 0, 0, 0);
            acc[1][0] = __builtin_amdgcn_mfma_f32_16x16x32_bf16(a1, b0, acc[1][0], 0, 0, 0);
            acc[1][1] = __builtin_amdgcn_mfma_f32_16x16x32_bf16(a1, b1, acc[1][1], 0, 0, 0);
        }
    }
    float* gp = Gpart + (size_t)quarter * 524288 + (size_t)bh * 4096;
    #pragma unroll
    for (int mi = 0; mi < 2; mi++)
        #pragma unroll
        for (int ni = 0; ni < 2; ni++)
            #pragma unroll
            for (int r = 0; r < 4; r++) {
                const int d = wr * 32 + mi * 16 + lg * 4 + r;
                const int e = wc * 32 + ni * 16 + l15;
                gp[d * 64 + e] = acc[mi][ni][r];
            }
}

// ---------------------------------------------------------------------------
// finalize: attnb[bh][d][e] = bf16( softmax_e( exp(scale_h)*G*rq[d]*rk[e] ) )
// ---------------------------------------------------------------------------
__global__ void attn_finalize_kernel(const float* __restrict__ Gpart,
                                     const float* __restrict__ Sq,
                                     const float* __restrict__ Sk,
                                     const float* __restrict__ scale,
                                     uint16_t* __restrict__ attnb) {
    const int bh = blockIdx.x;
    const int h = bh & 7;
    const int t = threadIdx.x;           // 256
    const int e = t & 63, w = t >> 6;
    const float es = expf(scale[h]);
    const float rk = rsqrtf(fmaxf(Sk[bh * 64 + e], 1.55e-5f));
    const float* g0 = Gpart + (size_t)bh * 4096;
    for (int d = w; d < 64; d += 4) {
        const float rq = rsqrtf(fmaxf(Sq[bh * 64 + d], 1.55e-5f));
        float g = g0[d * 64 + e] + g0[524288 + d * 64 + e]
                + g0[1048576 + d * 64 + e] + g0[1572864 + d * 64 + e];
        float x = es * g * rq * rk;
        float m = x;
        #pragma unroll
        for (int off = 32; off; off >>= 1) m = fmaxf(m, __shfl_xor(m, off, 64));
        float p = expf(x - m);
        float s = p;
        #pragma unroll
        for (int off = 32; off; off >>= 1) s += __shfl_xor(s, off, 64);
        attnb[(size_t)bh * 4096 + d * 64 + e] = f2bf(p / s);
    }
}

// ---------------------------------------------------------------------------
// pv (MFMA): out_t[n][h*64+d] = sum_e attnb[bh][d][e] * v[n][e]
// C staged through LDS -> packed b128 global stores (full 64B sectors).
// ---------------------------------------------------------------------------
__global__ __launch_bounds__(256) void pv_kernel(
        const uint16_t* __restrict__ VT, const uint16_t* __restrict__ attnb,
        uint16_t* __restrict__ out_t) {
    __shared__ uint16_t Vs[64 * 64];   // 8 KB
    __shared__ uint16_t Os[64 * 64];   // 8 KB
    const int blk = blockIdx.x;
    const int bh = blk >> 6, chunk = blk & 63;
    const int b = bh >> 3, h = bh & 7;
    const int n0 = chunk * 64;
    const int t = threadIdx.x, lane = t & 63, w = t >> 6;
    const int l15 = lane & 15, lg = lane >> 4;
    #pragma unroll
    for (int j = 0; j < 2; j++) {
        const int li = j * 256 + t;
        const int row = li >> 3;
        const int src_off = (((li & 7) ^ (row & 7)) << 3);
        gload16(VT + (size_t)(b * NTOK + n0 + row) * 512 + h * 64 + src_off, &Vs[li * 8]);
    }
    bf16x8 bfr[4][2];
    const uint16_t* ab = attnb + (size_t)bh * 4096;
    #pragma unroll
    for (int n = 0; n < 4; n++)
        #pragma unroll
        for (int ks = 0; ks < 2; ks++)
            bfr[n][ks] = *reinterpret_cast<const bf16x8*>(ab + (n * 16 + l15) * 64 + ks * 32 + lg * 8);
    __syncthreads();
    fx4 acc[4] = {};
    #pragma unroll
    for (int ks = 0; ks < 2; ks++) {
        const int row = w * 16 + l15;
        const int kof = ks * 32 + lg * 8;
        bf16x8 a = *reinterpret_cast<const bf16x8*>(&Vs[row * 64 + (kof ^ ((row & 7) << 3))]);
        #pragma unroll
        for (int n = 0; n < 4; n++)
            acc[n] = __builtin_amdgcn_mfma_f32_16x16x32_bf16(a, bfr[n][ks], acc[n], 0, 0, 0);
    }
    #pragma unroll
    for (int n = 0; n < 4; n++)
        #pragma unroll
        for (int r = 0; r < 4; r++) {
            const int row = w * 16 + lg * 4 + r;
            const int col = n * 16 + l15;
            Os[row * 64 + (col ^ ((row & 7) << 3))] = f2bf(acc[n][r]);
        }
    __syncthreads();
    {
        const int tr = t >> 2, c0 = (t & 3) * 16;
        uint16_t* orow = out_t + (size_t)(b * NTOK + n0 + tr) * CDIM + h * 64;
        #pragma unroll
        for (int cc2 = 0; cc2 < 2; cc2++) {
            const int c = c0 + cc2 * 8;
            const int chnk = (c >> 3) ^ (tr & 7);
            bf16x8 vv = *reinterpret_cast<const bf16x8*>(&Os[tr * 64 + (chnk << 3)]);
            *reinterpret_cast<bf16x8*>(orow + c) = vv;
        }
    }
}

// ---------------------------------------------------------------------------
// proj GEMM, 3-slot ring: out[M][512] = out_t @ Pt^T + proj_b (fp32 out)
// ---------------------------------------------------------------------------
__global__ __launch_bounds__(256) void gemm_proj_kernel(
        const uint16_t* __restrict__ At, const uint16_t* __restrict__ Pt,
        const float* __restrict__ proj_b, float* __restrict__ outp) {
    __shared__ uint16_t ring[3][8192];
    const int bx = blockIdx.x;
    const int swz = (bx & 7) * 256 + (bx >> 3);   // nwg=2048, bijective
    const int tn = swz & 3, tm = swz >> 2;
    const int gm = tm * 128, gn = tn * 128;
    const int t = threadIdx.x, lane = t & 63, w = t >> 6;
    const int wm = w >> 1, wn = w & 1;
    const int l15 = lane & 15, lg = lane >> 4;
    fx4 acc[4][4] = {};
    const int srow = t >> 2;
    const int scol = (((t & 3) ^ (srow & 3)) << 3);
    const uint16_t* gA = At + (size_t)(gm + srow) * 512 + scol;
    const uint16_t* gB = Pt + (size_t)(gn + srow) * 512 + scol;
    auto stage = [&](int kt_) {
        const int s_ = kt_ % 3;
        const int k0_ = kt_ * 32;
        gload16(gA + k0_,                    &ring[s_][t * 8]);
        gload16(gA + (size_t)64 * 512 + k0_, &ring[s_][t * 8 + 2048]);
        gload16(gB + k0_,                    &ring[s_][4096 + t * 8]);
        gload16(gB + (size_t)64 * 512 + k0_, &ring[s_][4096 + t * 8 + 2048]);
    };
    stage(0); stage(1);
    #pragma unroll
    for (int kt = 0; kt < 16; ++kt) {
        if (kt < 15) asm volatile("s_waitcnt vmcnt(4) lgkmcnt(0)" ::: "memory");
        else         asm volatile("s_waitcnt vmcnt(0) lgkmcnt(0)" ::: "memory");
        __builtin_amdgcn_s_barrier();
        if (kt < 14) stage(kt + 2);
        const uint16_t* As = &ring[kt % 3][0];
        const uint16_t* Bs = &ring[kt % 3][4096];
        bf16x8 af[4], bfr[4];
        #pragma unroll
        for (int m = 0; m < 4; m++) {
            const int row = wm * 64 + m * 16 + l15;
            af[m] = *reinterpret_cast<const bf16x8*>(&As[row * 32 + ((lg ^ (row & 3)) << 3)]);
        }
        #pragma unroll
        for (int n = 0; n < 4; n++) {
            const int row = wn * 64 + n * 16 + l15;
            bfr[n] = *reinterpret_cast<const bf16x8*>(&Bs[row * 32 + ((lg ^ (row & 3)) << 3)]);
        }
        __builtin_amdgcn_s_setprio(1);
        #pragma unroll
        for (int m = 0; m < 4; m++)
            #pragma unroll
            for (int n = 0; n < 4; n++)
                acc[m][n] = __builtin_amdgcn_mfma_f32_16x16x32_bf16(
                    af[m], bfr[n], acc[m][n], 0, 0, 0);
        __builtin_amdgcn_s_setprio(0);
    }
    #pragma unroll
    for (int m = 0; m < 4; m++) {
        #pragma unroll
        for (int n = 0; n < 4; n++) {
            const int col = gn + wn * 64 + n * 16 + l15;
            const float bias = proj_b[col];
            #pragma unroll
            for (int r = 0; r < 4; r++) {
                const int row = gm + wm * 64 + m * 16 + lg * 4 + r;
                outp[(size_t)row * CDIM + col] = acc[m][n][r] + bias;
            }
        }
    }
}

// ---------------------------------------------------------------------------
// ws layout (bytes):
//   0          Wt      1572864
//   1572864    Pt       524288
//   2097152    Sq        32768
//   2129920    Sk        32768
//   2162688    Gpart   8388608
//   10551296   attnb   1048576
//   11599872   QT     67108864   [bh][d][tok]
//   78708736   KT     67108864
//   145817600  VT     67108864   [token][c]
//   212926464  Xb/out_t 67108864 (disjoint-lifetime alias)
//   total 280035328 (~267 MB)
// ---------------------------------------------------------------------------
extern "C" void kernel_launch(void* const* d_in, const int* in_sizes, int n_in,
                              void* d_out, int out_size, void* d_ws, size_t ws_size,
                              hipStream_t stream) {
    (void)in_sizes; (void)n_in; (void)out_size; (void)ws_size;
    const float* x      = (const float*)d_in[0];
    const float* qkv_w  = (const float*)d_in[1];
    const float* q_bias = (const float*)d_in[2];
    const float* v_bias = (const float*)d_in[3];
    const float* scale  = (const float*)d_in[4];
    const float* proj_w = (const float*)d_in[5];
    const float* proj_b = (const float*)d_in[6];
    float* out = (float*)d_out;

    char* wsp = (char*)d_ws;
    uint16_t* Wt    = (uint16_t*)(wsp);
    uint16_t* Pt    = (uint16_t*)(wsp + 1572864);
    float*    Sq    = (float*)   (wsp + 2097152);
    float*    Sk    = (float*)   (wsp + 2129920);
    float*    Gpart = (float*)   (wsp + 2162688);
    uint16_t* attnb = (uint16_t*)(wsp + 10551296);
    uint16_t* QT    = (uint16_t*)(wsp + 11599872);
    uint16_t* KT    = (uint16_t*)(wsp + 78708736);
    uint16_t* VT    = (uint16_t*)(wsp + 145817600);
    uint16_t* Xb    = (uint16_t*)(wsp + 212926464);
    uint16_t* out_t = Xb;   // disjoint lifetime alias

    hipLaunchKernelGGL(transpose_w_kernel, dim3(1024), dim3(256), 0, stream,
                       qkv_w, proj_w, Wt, Pt);
    hipLaunchKernelGGL(prep_kernel, dim3(2048), dim3(256), 0, stream,
                       x, Xb, Sq);
    hipLaunchKernelGGL(gemm_qkv_kernel, dim3(6144), dim3(256), 0, stream,
                       Xb, Wt, q_bias, v_bias, QT, KT, VT, Sq, Sk);
    hipLaunchKernelGGL(attn_qk_kernel, dim3(512), dim3(256), 0, stream,
                       QT, KT, Gpart);
    hipLaunchKernelGGL(attn_finalize_kernel, dim3(128), dim3(256), 0, stream,
                       Gpart, Sq, Sk, scale, attnb);
    hipLaunchKernelGGL(pv_kernel, dim3(8192), dim3(256), 0, stream,
                       VT, attnb, out_t);
    hipLaunchKernelGGL(gemm_proj_kernel, dim3(2048), dim3(256), 0, stream,
                       out_t, Pt, proj_b, out);
}